// Round 5
// baseline (333.130 us; speedup 1.0000x reference)
//
#include <hip/hip_runtime.h>
#include <hip/hip_bf16.h>
#include <cstdint>

#define T_TOK 4096
#define H_DIM 1024
#define F_DIM 2048
#define E_NUM 8
#define MAXT256 39
#define MAXROWS (MAXT256*256)   // 9984 padded entry rows

typedef __attribute__((ext_vector_type(8))) short bf16x8;
typedef __attribute__((ext_vector_type(4))) float f32x4;

__device__ __forceinline__ unsigned short f2bf(float f){
  union { float f; uint32_t u; } c; c.f = f;
  uint32_t u = c.u;
  uint32_t r = (u + 0x7fffu + ((u >> 16) & 1u)) >> 16;
  return (unsigned short)r;
}

// ---------------- weights fp32 -> bf16 (one kernel, 3 segments) -------------
__global__ __launch_bounds__(256) void k_wcvt(const float* __restrict__ w1,
                                              const float* __restrict__ w3,
                                              const float* __restrict__ w2,
                                              unsigned short* __restrict__ w1b,
                                              unsigned short* __restrict__ w3b,
                                              unsigned short* __restrict__ w2b){
  int seg = blockIdx.x >> 11;
  int b   = blockIdx.x & 2047;
  const float* s = seg==0 ? w1 : (seg==1 ? w3 : w2);
  unsigned short* d = seg==0 ? w1b : (seg==1 ? w3b : w2b);
  const int n4 = E_NUM*F_DIM*H_DIM/4;
  for (int i = b*256 + threadIdx.x; i < n4; i += 2048*256){
    float4 v = reinterpret_cast<const float4*>(s)[i];
    ushort4 o;
    o.x = f2bf(v.x); o.y = f2bf(v.y); o.z = f2bf(v.z); o.w = f2bf(v.w);
    reinterpret_cast<ushort4*>(d)[i] = o;
  }
}

// ------- router: 32 tokens/block, 8 lanes/token, rw staged in LDS -----------
__global__ __launch_bounds__(256) void k_router(const float* __restrict__ x,
                                               const float* __restrict__ rw,
                                               int* __restrict__ counts,
                                               int* __restrict__ topi,
                                               float* __restrict__ topv,
                                               unsigned short* __restrict__ xb){
  __shared__ float lrw[E_NUM][8][132];
  __shared__ int hist[E_NUM];
  int tid = threadIdx.x;
  if (tid < E_NUM) hist[tid] = 0;
  for (int i = tid; i < E_NUM*H_DIM/4; i += 256){
    int idx = i*4;
    int e = idx >> 10, rem = idx & 1023, c = rem >> 7, j = rem & 127;
    float4 v = reinterpret_cast<const float4*>(rw)[i];
    *reinterpret_cast<float4*>(&lrw[e][c][j]) = v;
  }
  __syncthreads();

  int t = blockIdx.x*32 + (tid >> 3);
  int c = tid & 7;
  const float4* xr = reinterpret_cast<const float4*>(x + (size_t)t*H_DIM + c*128);
  ushort4* xw = reinterpret_cast<ushort4*>(xb + (size_t)t*H_DIM + c*128);
  double acc[E_NUM];
#pragma unroll
  for (int e=0;e<E_NUM;e++) acc[e] = 0.0;
  for (int j4=0; j4<32; ++j4){
    float4 v = xr[j4];
    ushort4 o;
    o.x = f2bf(v.x); o.y = f2bf(v.y); o.z = f2bf(v.z); o.w = f2bf(v.w);
    xw[j4] = o;
#pragma unroll
    for (int e=0;e<E_NUM;e++){
      float4 r = *reinterpret_cast<const float4*>(&lrw[e][c][j4*4]);
      acc[e] += (double)v.x*(double)r.x + (double)v.y*(double)r.y
              + (double)v.z*(double)r.z + (double)v.w*(double)r.w;
    }
  }
#pragma unroll
  for (int e=0;e<E_NUM;e++){
    double s = acc[e];
    s += __shfl_xor(s, 1, 64);
    s += __shfl_xor(s, 2, 64);
    s += __shfl_xor(s, 4, 64);
    acc[e] = s;
  }
  if (c == 0){
    int i0 = 0; double v0 = acc[0];
    for (int e=1;e<E_NUM;e++) if (acc[e] > v0){ v0 = acc[e]; i0 = e; }
    int i1 = -1; double v1 = -1e300;
    for (int e=0;e<E_NUM;e++) if (e != i0 && acc[e] > v1){ v1 = acc[e]; i1 = e; }
    float w0 = 1.0f/(1.0f + expf((float)(v1 - v0)));
    topi[2*t] = i0; topi[2*t+1] = i1;
    topv[2*t] = w0; topv[2*t+1] = 1.0f - w0;
    atomicAdd(&hist[i0], 1); atomicAdd(&hist[i1], 1);
  }
  __syncthreads();
  if (tid < E_NUM && hist[tid]) atomicAdd(&counts[tid], hist[tid]);
}

// ---------------- per-expert padded tile offsets (256-granular) -------------
__global__ void k_offsets(const int* __restrict__ counts,
                          int* __restrict__ ts256, int* __restrict__ cursors){
  if (threadIdx.x == 0){
    int b = 0;
    for (int e=0;e<E_NUM;e++){ ts256[e] = b; b += (counts[e] + 255) >> 8; }
    ts256[E_NUM] = b;
  }
  if (threadIdx.x < E_NUM) cursors[threadIdx.x] = 0;
}

// ---------------- fill grouped entry lists ----------------------------------
__global__ __launch_bounds__(256) void k_fill(const int* __restrict__ topi,
                                              const int* __restrict__ ts256,
                                              int* __restrict__ cursors,
                                              int* __restrict__ entries){
  int t = blockIdx.x*256 + threadIdx.x;
  if (t >= T_TOK) return;
#pragma unroll
  for (int k=0;k<2;k++){
    int e = topi[2*t+k];
    int pos = atomicAdd(&cursors[e], 1);
    entries[ts256[e]*256 + pos] = 2*t + k;
  }
}

// ---------------- shared sync / staging macros ------------------------------
#define GLD(src, dst_us) __builtin_amdgcn_global_load_lds( \
  (const __attribute__((address_space(1))) unsigned int*)(src), \
  (__attribute__((address_space(3))) unsigned int*)(lds + (dst_us)), 16, 0, 0)

#define VMW(N) asm volatile("s_waitcnt vmcnt(" #N ")" ::: "memory")
#define BARS do{ __builtin_amdgcn_s_barrier(); __builtin_amdgcn_sched_barrier(0); }while(0)
#define MMGO do{ asm volatile("s_waitcnt lgkmcnt(0)" ::: "memory"); \
  __builtin_amdgcn_sched_barrier(0); __builtin_amdgcn_s_setprio(1); }while(0)
#define MMEND __builtin_amdgcn_s_setprio(0)

// ---------------- phase 1: 256x256 grouped GEMM + SiLU, 8-phase -------------
// 2 K-tiles/iteration (buf0=even tile, buf1=odd), 8 phases, vmcnt(6) only at
// P4/P8. Stage a quarter strictly one phase after its last ds_read (safe via
// trailing barrier). Parts per 64KiB buffer: 0=A0,1=A1,2=B0(w1),3=B1(w3).

#define STG(X, s0, s1, dbS, kS) do{ \
  GLD((s0) + (kS)*64, (dbS)*32768 + (X)*8192 + dstb0); \
  GLD((s1) + (kS)*64, (dbS)*32768 + (X)*8192 + dstb1); }while(0)

#define LDA(db, QR) do{ const char* p_ = (const char*)lds + ((db)*4 + (QR))*16384; \
  _Pragma("unroll") for (int m_=0;m_<4;m_++) \
  _Pragma("unroll") for (int ks_=0;ks_<2;ks_++) \
    a[m_][ks_] = *(const bf16x8*)(p_ + aoff[m_][ks_]); }while(0)

#define LDB(db, QC, breg) do{ const char* p_ = (const char*)lds + ((db)*4 + 2 + (QC))*16384; \
  _Pragma("unroll") for (int n_=0;n_<2;n_++) \
  _Pragma("unroll") for (int ks_=0;ks_<2;ks_++) \
    breg[n_][ks_] = *(const bf16x8*)(p_ + boff[n_][ks_]); }while(0)

#define MM(QR, QC, breg) do{ \
  _Pragma("unroll") for (int m_=0;m_<4;m_++) \
  _Pragma("unroll") for (int n_=0;n_<2;n_++) \
  _Pragma("unroll") for (int ks_=0;ks_<2;ks_++) \
    acc[QR][QC][m_][n_] = __builtin_amdgcn_mfma_f32_16x16x32_bf16(a[m_][ks_], breg[n_][ks_], acc[QR][QC][m_][n_], 0,0,0); }while(0)

__global__ __launch_bounds__(512) void k_ffn1(const unsigned short* __restrict__ xb,
                                              const unsigned short* __restrict__ w1b,
                                              const unsigned short* __restrict__ w3b,
                                              const int* __restrict__ ts256,
                                              const int* __restrict__ counts,
                                              const int* __restrict__ entries,
                                              unsigned short* __restrict__ hidden){
  extern __shared__ unsigned short lds[];
  int flat = blockIdx.x;
  int nw = (flat & 7)*78 + (flat >> 3);     // 624 = 8*78 bijective XCD chunking
  int tile = nw % MAXT256;
  int nt   = nw / MAXT256;
  if (tile >= ts256[E_NUM]) return;
  int e = 0;
  for (int i=E_NUM-1;i>=0;i--) if (tile >= ts256[i]){ e = i; break; }
  int n_e  = counts[e];
  int row0 = (tile - ts256[e])*256;
  int ebase = ts256[e]*256;

  int tid = threadIdx.x, lane = tid & 63, wid = tid >> 6;
  int wm = wid >> 2, wn = wid & 3;          // 2 x 4 wave grid

  const unsigned short* sA[2][2];
  const unsigned short* sB[2][2];
#pragma unroll
  for (int h=0;h<2;h++){
#pragma unroll
    for (int i=0;i<2;i++){
      int idx = i*512 + tid;
      int r = idx >> 3, seg = idx & 7;
      int sc = (seg ^ (r & 7))*8;
      int br = ((r>>6)<<7) | (h<<6) | (r & 63);   // interleaved A halves (bit6)
      int rr = row0 + br; rr = rr < n_e ? rr : (n_e - 1);
      int tokr = entries[ebase + rr] >> 1;
      sA[h][i] = xb + (size_t)tokr*H_DIM + sc;
      const unsigned short* w = h ? w3b : w1b;    // B part2=w1(gate), part3=w3(up)
      sB[h][i] = w + ((size_t)e*F_DIM + nt*128 + r)*H_DIM + sc;
    }
  }
  int dstb0 = wid*512;
  int dstb1 = 4096 + wid*512;

  int aoff[4][2], boff[2][2];
#pragma unroll
  for (int m=0;m<4;m++){
    int ia = wm*64 + m*16 + (lane & 15);
#pragma unroll
    for (int ks=0;ks<2;ks++)
      aoff[m][ks] = ia*128 + ((ks*64 + (lane>>4)*16) ^ ((ia & 7) << 4));
  }
#pragma unroll
  for (int n=0;n<2;n++){
    int ib = wn*32 + n*16 + (lane & 15);
#pragma unroll
    for (int ks=0;ks<2;ks++)
      boff[n][ks] = ib*128 + ((ks*64 + (lane>>4)*16) ^ ((ib & 7) << 4));
  }

  f32x4 acc[2][2][4][2];
#pragma unroll
  for (int qr=0;qr<2;qr++)
#pragma unroll
  for (int qc=0;qc<2;qc++)
#pragma unroll
  for (int m=0;m<4;m++)
#pragma unroll
  for (int n=0;n<2;n++) acc[qr][qc][m][n] = {0.f,0.f,0.f,0.f};

  bf16x8 a[4][2], bA[2][2], bB[2][2];

  // prologue: stage tiles 0 (buf0) and 1 (buf1) fully
  STG(0, sA[0][0], sA[0][1], 0, 0);
  STG(2, sB[0][0], sB[0][1], 0, 0);
  STG(3, sB[1][0], sB[1][1], 0, 0);
  STG(1, sA[1][0], sA[1][1], 0, 0);
  STG(0, sA[0][0], sA[0][1], 1, 1);
  STG(2, sB[0][0], sB[0][1], 1, 1);
  STG(3, sB[1][0], sB[1][1], 1, 1);
  STG(1, sA[1][0], sA[1][1], 1, 1);
  VMW(8);         // tile0 complete; tile1's 8 still in flight
  BARS;

  for (int t=0; t<7; ++t){
    int kW = 2*t+2, kX = 2*t+3;
    // P1: read A0,B0 (buf0); 16 MFMA
    LDA(0,0); LDB(0,0,bA);
    BARS; MMGO; MM(0,0,bA); MMEND; BARS;
    // P2: read B1; stage w.A0->p0, w.B0->p2 (freed in P1)
    LDB(0,1,bB);
    STG(0, sA[0][0], sA[0][1], 0, kW);
    STG(2, sB[0][0], sB[0][1], 0, kW);
    BARS; MMGO; MM(0,1,bB); MMEND; BARS;
    // P3: read A1; stage w.B1->p3 (freed in P2)
    LDA(0,1);
    STG(3, sB[1][0], sB[1][1], 0, kW);
    BARS; MMGO; MM(1,0,bA); MMEND; BARS;
    // P4: stage w.A1->p1 (freed in P3); vmcnt(6) -> tile 2t+1 fully present
    STG(1, sA[1][0], sA[1][1], 0, kW);
    VMW(6);
    BARS; MMGO; MM(1,1,bB); MMEND; BARS;
    // P5: read A0,B0 (buf1)
    LDA(1,0); LDB(1,0,bA);
    BARS; MMGO; MM(0,0,bA); MMEND; BARS;
    // P6: read B1; stage x.A0,x.B0
    LDB(1,1,bB);
    STG(0, sA[0][0], sA[0][1], 1, kX);
    STG(2, sB[0][0], sB[0][1], 1, kX);
    BARS; MMGO; MM(0,1,bB); MMEND; BARS;
    // P7: read A1; stage x.B1
    LDA(1,1);
    STG(3, sB[1][0], sB[1][1], 1, kX);
    BARS; MMGO; MM(1,0,bA); MMEND; BARS;
    // P8: stage x.A1; vmcnt(6) -> tile 2t+2 fully present
    STG(1, sA[1][0], sA[1][1], 1, kX);
    VMW(6);
    BARS; MMGO; MM(1,1,bB); MMEND; BARS;
  }
  // epilogue: tiles 14 (buf0), 15 (buf1), no staging
  LDA(0,0); LDB(0,0,bA); BARS; MMGO; MM(0,0,bA); MMEND; BARS;
  LDB(0,1,bB);           BARS; MMGO; MM(0,1,bB); MMEND; BARS;
  LDA(0,1);              BARS; MMGO; MM(1,0,bA); MMEND; BARS;
  VMW(0);                BARS; MMGO; MM(1,1,bB); MMEND; BARS;
  LDA(1,0); LDB(1,0,bA); BARS; MMGO; MM(0,0,bA); MMEND; BARS;
  LDB(1,1,bB);           BARS; MMGO; MM(0,1,bB); MMEND; BARS;
  LDA(1,1);              BARS; MMGO; MM(1,0,bA); MMEND; BARS;
                               MMGO; MM(1,1,bB); MMEND;

  // SiLU epilogue: gate=acc[qr][0], up=acc[qr][1]
  int r16 = ((lane >> 4) & 3)*4;
#pragma unroll
  for (int qr=0;qr<2;qr++){
#pragma unroll
    for (int m=0;m<4;m++){
#pragma unroll
      for (int j=0;j<4;j++){
        int br = wm*128 + qr*64 + m*16 + r16 + j;
        if (row0 + br < n_e){
          size_t rowbase = (size_t)(ebase + row0 + br)*F_DIM + nt*128 + wn*32;
#pragma unroll
          for (int n=0;n<2;n++){
            float g = acc[qr][0][m][n][j];
            float u = acc[qr][1][m][n][j];
            float h = (g / (1.f + __expf(-g))) * u;
            hidden[rowbase + n*16 + (lane & 15)] = f2bf(h);
          }
        }
      }
    }
  }
}

// ---------------- phase 2: 256x128 grouped GEMM + combine, triple-buffer ----
// Tile 256 rows x 128 cols, K-tiles=32 (BK=64). 3 LDS buffers (144 KiB),
// stage 2 tiles ahead, vmcnt(6) once per K-tile. Parts: 0=A0,1=A1,2=B.
// Grid 312 = 8 XCD x 39: nt == XCD -> each 4MB w2 panel = its own L2.

#define STG2(P, s0, s1, bufS, kS) do{ \
  GLD((s0) + (kS)*64, (bufS)*24576 + (P)*8192 + dstb0); \
  GLD((s1) + (kS)*64, (bufS)*24576 + (P)*8192 + dstb1); }while(0)

#define LDA2(buf, QR) do{ const char* p_ = (const char*)lds + (buf)*49152 + (QR)*16384; \
  _Pragma("unroll") for (int m_=0;m_<4;m_++) \
  _Pragma("unroll") for (int ks_=0;ks_<2;ks_++) \
    a[m_][ks_] = *(const bf16x8*)(p_ + aoff[m_][ks_]); }while(0)

#define LDB2(buf) do{ const char* p_ = (const char*)lds + (buf)*49152 + 32768; \
  _Pragma("unroll") for (int n_=0;n_<2;n_++) \
  _Pragma("unroll") for (int ks_=0;ks_<2;ks_++) \
    b[n_][ks_] = *(const bf16x8*)(p_ + boff[n_][ks_]); }while(0)

#define MM2(QR) do{ \
  _Pragma("unroll") for (int m_=0;m_<4;m_++) \
  _Pragma("unroll") for (int n_=0;n_<2;n_++) \
  _Pragma("unroll") for (int ks_=0;ks_<2;ks_++) \
    acc[QR][m_][n_] = __builtin_amdgcn_mfma_f32_16x16x32_bf16(a[m_][ks_], b[n_][ks_], acc[QR][m_][n_], 0,0,0); }while(0)

// one K-tile: CUR = its buffer, ST = (CUR+2)%3 target for tile KT=k+2
#define F2TILE(CUR, ST, KT) do{ \
  VMW(6); \
  LDA2(CUR,0); LDB2(CUR); \
  STG2(0, sA[0][0], sA[0][1], ST, KT); \
  STG2(2, sB[0],    sB[1],    ST, KT); \
  BARS; MMGO; MM2(0); MMEND; BARS; \
  LDA2(CUR,1); \
  STG2(1, sA[1][0], sA[1][1], ST, KT); \
  BARS; MMGO; MM2(1); MMEND; BARS; }while(0)

__global__ __launch_bounds__(512) void k_ffn2(const unsigned short* __restrict__ hidden,
                                              const unsigned short* __restrict__ w2b,
                                              const int* __restrict__ ts256,
                                              const int* __restrict__ counts,
                                              const int* __restrict__ entries,
                                              const float* __restrict__ topv,
                                              float* __restrict__ out){
  extern __shared__ unsigned short lds[];   // 3 * 24576 ushorts = 144 KiB
  int flat = blockIdx.x;
  int nw = (flat & 7)*MAXT256 + (flat >> 3);  // 312 = 8*39 bijective
  int tile = nw % MAXT256;
  int nt   = nw / MAXT256;                    // nt == XCD index
  if (tile >= ts256[E_NUM]) return;
  int e = 0;
  for (int i=E_NUM-1;i>=0;i--) if (tile >= ts256[i]){ e = i; break; }
  int n_e  = counts[e];
  int row0 = (tile - ts256[e])*256;
  int ebase = ts256[e]*256;

  int tid = threadIdx.x, lane = tid & 63, wid = tid >> 6;
  int wm = wid >> 2, wn = wid & 3;            // 2 x 4 wave grid

  const unsigned short* sA[2][2];
  const unsigned short* sB[2];
#pragma unroll
  for (int h=0;h<2;h++){
#pragma unroll
    for (int i=0;i<2;i++){
      int idx = i*512 + tid;
      int r = idx >> 3, seg = idx & 7;
      int sc = (seg ^ (r & 7))*8;
      int br = ((r>>6)<<7) | (h<<6) | (r & 63);
      sA[h][i] = hidden + (size_t)(ebase + row0 + br)*F_DIM + sc;  // padded rows: stale data, outputs discarded
    }
  }
#pragma unroll
  for (int i=0;i<2;i++){
    int idx = i*512 + tid;
    int r = idx >> 3, seg = idx & 7;
    int sc = (seg ^ (r & 7))*8;
    sB[i] = w2b + ((size_t)e*H_DIM + nt*128 + r)*F_DIM + sc;
  }
  int dstb0 = wid*512;
  int dstb1 = 4096 + wid*512;

  int aoff[4][2], boff[2][2];
#pragma unroll
  for (int m=0;m<4;m++){
    int ia = wm*64 + m*16 + (lane & 15);
#pragma unroll
    for (int ks=0;ks<2;ks++)
      aoff[m][ks] = ia*128 + ((ks*64 + (lane>>4)*16) ^ ((ia & 7) << 4));
  }
#pragma unroll
  for (int n=0;n<2;n++){
    int ib = wn*32 + n*16 + (lane & 15);
#pragma unroll
    for (int ks=0;ks<2;ks++)
      boff[n][ks] = ib*128 + ((ks*64 + (lane>>4)*16) ^ ((ib & 7) << 4));
  }

  f32x4 acc[2][4][2];
#pragma unroll
  for (int qr=0;qr<2;qr++)
#pragma unroll
  for (int m=0;m<4;m++)
#pragma unroll
  for (int n=0;n<2;n++) acc[qr][m][n] = {0.f,0.f,0.f,0.f};

  bf16x8 a[4][2], b[2][2];

  // prologue: stage tiles 0 (buf0) and 1 (buf1)
  STG2(0, sA[0][0], sA[0][1], 0, 0);
  STG2(2, sB[0],    sB[1],    0, 0);
  STG2(1, sA[1][0], sA[1][1], 0, 0);
  STG2(0, sA[0][0], sA[0][1], 1, 1);
  STG2(2, sB[0],    sB[1],    1, 1);
  STG2(1, sA[1][0], sA[1][1], 1, 1);
  VMW(6);    // tile0 complete
  BARS;

  for (int kk=0; kk<30; kk+=3){
    F2TILE(0, 2, kk+2);
    F2TILE(1, 0, kk+3);
    F2TILE(2, 1, kk+4);
  }
  // k=30 (buf0): no staging
  VMW(6);
  LDA2(0,0); LDB2(0); BARS; MMGO; MM2(0); MMEND; BARS;
  LDA2(0,1);          BARS; MMGO; MM2(1); MMEND; BARS;
  // k=31 (buf1): drain
  VMW(0);
  LDA2(1,0); LDB2(1); BARS; MMGO; MM2(0); MMEND; BARS;
  LDA2(1,1);                MMGO; MM2(1); MMEND;

  // weighted combine via fp32 atomics (each out elem gets exactly 2 adds)
  int r16 = ((lane >> 4) & 3)*4;
#pragma unroll
  for (int qr=0;qr<2;qr++){
#pragma unroll
    for (int m=0;m<4;m++){
#pragma unroll
      for (int j=0;j<4;j++){
        int gr = row0 + wm*128 + qr*64 + m*16 + r16 + j;
        if (gr < n_e){
          int packed = entries[ebase + gr];
          int t = packed >> 1;
          float w = topv[packed];
#pragma unroll
          for (int n=0;n<2;n++){
            int col = nt*128 + wn*32 + n*16 + (lane & 15);
            atomicAdd(&out[(size_t)t*H_DIM + col], w * acc[qr][m][n][j]);
          }
        }
      }
    }
  }
}

// ---------------------------------------------------------------------------
extern "C" void kernel_launch(void* const* d_in, const int* in_sizes, int n_in,
                              void* d_out, int out_size, void* d_ws, size_t ws_size,
                              hipStream_t stream){
  const float* x  = (const float*)d_in[0];
  const float* rw = (const float*)d_in[1];
  const float* w1 = (const float*)d_in[2];
  const float* w2 = (const float*)d_in[3];
  const float* w3 = (const float*)d_in[4];
  float* out = (float*)d_out;

  char* ws = (char*)d_ws;
  size_t off = 0;
  unsigned short* xb  = (unsigned short*)(ws + off); off += (size_t)T_TOK*H_DIM*2;
  unsigned short* w1b = (unsigned short*)(ws + off); off += (size_t)E_NUM*F_DIM*H_DIM*2;
  unsigned short* w3b = (unsigned short*)(ws + off); off += (size_t)E_NUM*F_DIM*H_DIM*2;
  unsigned short* w2b = (unsigned short*)(ws + off); off += (size_t)E_NUM*H_DIM*F_DIM*2;
  unsigned short* hidden = (unsigned short*)(ws + off); off += (size_t)MAXROWS*F_DIM*2;
  int*   counts  = (int*)(ws + off); off += 64;
  int*   ts256   = (int*)(ws + off); off += 64;
  int*   cursors = (int*)(ws + off); off += 64;
  int*   topi    = (int*)(ws + off); off += (size_t)T_TOK*2*4;
  float* topv    = (float*)(ws + off); off += (size_t)T_TOK*2*4;
  int*   entries = (int*)(ws + off); off += (size_t)MAXROWS*4;

  hipFuncSetAttribute((const void*)k_ffn1,
                      hipFuncAttributeMaxDynamicSharedMemorySize, 131072);
  hipFuncSetAttribute((const void*)k_ffn2,
                      hipFuncAttributeMaxDynamicSharedMemorySize, 147456);

  hipMemsetAsync(counts, 0, 32, stream);
  hipMemsetAsync(out, 0, (size_t)out_size*sizeof(float), stream);

  k_router<<<T_TOK/32, 256, 0, stream>>>(x, rw, counts, topi, topv, xb);
  k_offsets<<<1, 64, 0, stream>>>(counts, ts256, cursors);
  k_fill<<<T_TOK/256, 256, 0, stream>>>(topi, ts256, cursors, entries);
  k_wcvt<<<3*2048, 256, 0, stream>>>(w1, w3, w2, w1b, w3b, w2b);

  k_ffn1<<<MAXT256*16, 512, 131072, stream>>>(xb, w1b, w3b, ts256, counts, entries, hidden);
  k_ffn2<<<MAXT256*8, 512, 147456, stream>>>(hidden, w2b, ts256, counts, entries, topv, out);
}

// Round 6
// 326.022 us; speedup vs baseline: 1.0218x; 1.0218x over previous
//
#include <hip/hip_runtime.h>
#include <hip/hip_bf16.h>
#include <cstdint>

#define T_TOK 4096
#define H_DIM 1024
#define F_DIM 2048
#define E_NUM 8
#define MAXT256 39
#define MAXROWS (MAXT256*256)   // 9984 padded entry rows

typedef __attribute__((ext_vector_type(8))) short bf16x8;
typedef __attribute__((ext_vector_type(4))) float f32x4;

__device__ __forceinline__ unsigned short f2bf(float f){
  union { float f; uint32_t u; } c; c.f = f;
  uint32_t u = c.u;
  uint32_t r = (u + 0x7fffu + ((u >> 16) & 1u)) >> 16;
  return (unsigned short)r;
}

// expert lookup from counts via unrolled prefix (no k_offsets kernel needed)
#define EXPERT_PREFIX(tile, counts, e, ts_e, n_e, btot) do{ \
  btot = 0; e = 0; ts_e = 0; n_e = 0; \
  _Pragma("unroll") for (int i_=0;i_<E_NUM;i_++){ \
    int cnt_ = (counts)[i_]; \
    if ((tile) >= btot){ e = i_; ts_e = btot; n_e = cnt_; } \
    btot += (cnt_ + 255) >> 8; } }while(0)

// ---- weights fp32 -> bf16 (3 segments) + zero counts/cursors + zero out ----
__global__ __launch_bounds__(256) void k_wcvt(const float* __restrict__ w1,
                                              const float* __restrict__ w3,
                                              const float* __restrict__ w2,
                                              unsigned short* __restrict__ w1b,
                                              unsigned short* __restrict__ w3b,
                                              unsigned short* __restrict__ w2b,
                                              float* __restrict__ out,
                                              int* __restrict__ zbase){
  int tid = threadIdx.x;
  if (blockIdx.x == 0 && tid < 32) zbase[tid] = 0;   // counts[16] + cursors[16]
  float4 z4 = {0.f,0.f,0.f,0.f};
  for (int i = blockIdx.x*256 + tid; i < T_TOK*H_DIM/4; i += 6144*256)
    reinterpret_cast<float4*>(out)[i] = z4;
  int seg = blockIdx.x >> 11;
  int b   = blockIdx.x & 2047;
  const float* s = seg==0 ? w1 : (seg==1 ? w3 : w2);
  unsigned short* d = seg==0 ? w1b : (seg==1 ? w3b : w2b);
  const int n4 = E_NUM*F_DIM*H_DIM/4;
  for (int i = b*256 + tid; i < n4; i += 2048*256){
    float4 v = reinterpret_cast<const float4*>(s)[i];
    ushort4 o;
    o.x = f2bf(v.x); o.y = f2bf(v.y); o.z = f2bf(v.z); o.w = f2bf(v.w);
    reinterpret_cast<ushort4*>(d)[i] = o;
  }
}

// ------- router: 32 tokens/block, 8 lanes/token, rw staged in LDS -----------
__global__ __launch_bounds__(256) void k_router(const float* __restrict__ x,
                                               const float* __restrict__ rw,
                                               int* __restrict__ counts,
                                               int* __restrict__ topi,
                                               float* __restrict__ topv,
                                               unsigned short* __restrict__ xb){
  __shared__ float lrw[E_NUM][8][132];
  __shared__ int hist[E_NUM];
  int tid = threadIdx.x;
  if (tid < E_NUM) hist[tid] = 0;
  for (int i = tid; i < E_NUM*H_DIM/4; i += 256){
    int idx = i*4;
    int e = idx >> 10, rem = idx & 1023, c = rem >> 7, j = rem & 127;
    float4 v = reinterpret_cast<const float4*>(rw)[i];
    *reinterpret_cast<float4*>(&lrw[e][c][j]) = v;
  }
  __syncthreads();

  int t = blockIdx.x*32 + (tid >> 3);
  int c = tid & 7;
  const float4* xr = reinterpret_cast<const float4*>(x + (size_t)t*H_DIM + c*128);
  ushort4* xw = reinterpret_cast<ushort4*>(xb + (size_t)t*H_DIM + c*128);
  double acc[E_NUM];
#pragma unroll
  for (int e=0;e<E_NUM;e++) acc[e] = 0.0;
  for (int j4=0; j4<32; ++j4){
    float4 v = xr[j4];
    ushort4 o;
    o.x = f2bf(v.x); o.y = f2bf(v.y); o.z = f2bf(v.z); o.w = f2bf(v.w);
    xw[j4] = o;
#pragma unroll
    for (int e=0;e<E_NUM;e++){
      float4 r = *reinterpret_cast<const float4*>(&lrw[e][c][j4*4]);
      acc[e] += (double)v.x*(double)r.x + (double)v.y*(double)r.y
              + (double)v.z*(double)r.z + (double)v.w*(double)r.w;
    }
  }
#pragma unroll
  for (int e=0;e<E_NUM;e++){
    double s = acc[e];
    s += __shfl_xor(s, 1, 64);
    s += __shfl_xor(s, 2, 64);
    s += __shfl_xor(s, 4, 64);
    acc[e] = s;
  }
  if (c == 0){
    int i0 = 0; double v0 = acc[0];
    for (int e=1;e<E_NUM;e++) if (acc[e] > v0){ v0 = acc[e]; i0 = e; }
    int i1 = -1; double v1 = -1e300;
    for (int e=0;e<E_NUM;e++) if (e != i0 && acc[e] > v1){ v1 = acc[e]; i1 = e; }
    float w0 = 1.0f/(1.0f + expf((float)(v1 - v0)));
    topi[2*t] = i0; topi[2*t+1] = i1;
    topv[2*t] = w0; topv[2*t+1] = 1.0f - w0;
    atomicAdd(&hist[i0], 1); atomicAdd(&hist[i1], 1);
  }
  __syncthreads();
  if (tid < E_NUM && hist[tid]) atomicAdd(&counts[tid], hist[tid]);
}

// ---------------- fill grouped entry lists (prefix computed locally) --------
__global__ __launch_bounds__(256) void k_fill(const int* __restrict__ topi,
                                              const int* __restrict__ counts,
                                              int* __restrict__ cursors,
                                              int* __restrict__ entries){
  __shared__ int ts[E_NUM];
  if (threadIdx.x == 0){
    int b = 0;
    for (int e=0;e<E_NUM;e++){ ts[e] = b; b += (counts[e] + 255) >> 8; }
  }
  __syncthreads();
  int t = blockIdx.x*256 + threadIdx.x;
  if (t >= T_TOK) return;
#pragma unroll
  for (int k=0;k<2;k++){
    int e = topi[2*t+k];
    int pos = atomicAdd(&cursors[e], 1);
    entries[ts[e]*256 + pos] = 2*t + k;
  }
}

// ---------------- shared sync / staging macros ------------------------------
#define GLD(src, dst_us) __builtin_amdgcn_global_load_lds( \
  (const __attribute__((address_space(1))) unsigned int*)(src), \
  (__attribute__((address_space(3))) unsigned int*)(lds + (dst_us)), 16, 0, 0)

#define VMW(N) asm volatile("s_waitcnt vmcnt(" #N ")" ::: "memory")
#define BARS do{ __builtin_amdgcn_s_barrier(); __builtin_amdgcn_sched_barrier(0); }while(0)
#define MMGO do{ asm volatile("s_waitcnt lgkmcnt(0)" ::: "memory"); \
  __builtin_amdgcn_sched_barrier(0); __builtin_amdgcn_s_setprio(1); }while(0)
#define MMEND __builtin_amdgcn_s_setprio(0)

// ---------------- phase 1: 256x256 grouped GEMM + SiLU (round-4 schedule) ---
// 3 phases/K-tile, VMW(4)/VMW(6)/VMW(8), one barrier per phase, stage into
// the other dbuf. Parts per 64KiB buffer: 0=A0,1=A1,2=B0(w1),3=B1(w3).

#define STG(X, s0, s1, dbS, kS) do{ \
  GLD((s0) + (kS)*64, (dbS)*32768 + (X)*8192 + dstb0); \
  GLD((s1) + (kS)*64, (dbS)*32768 + (X)*8192 + dstb1); }while(0)

#define LDA(db, QR) do{ const char* p_ = (const char*)lds + ((db)*4 + (QR))*16384; \
  _Pragma("unroll") for (int m_=0;m_<4;m_++) \
  _Pragma("unroll") for (int ks_=0;ks_<2;ks_++) \
    a[m_][ks_] = *(const bf16x8*)(p_ + aoff[m_][ks_]); }while(0)

#define LDB(db, QC, breg) do{ const char* p_ = (const char*)lds + ((db)*4 + 2 + (QC))*16384; \
  _Pragma("unroll") for (int n_=0;n_<2;n_++) \
  _Pragma("unroll") for (int ks_=0;ks_<2;ks_++) \
    breg[n_][ks_] = *(const bf16x8*)(p_ + boff[n_][ks_]); }while(0)

#define MM(QR, QC, breg) do{ \
  _Pragma("unroll") for (int m_=0;m_<4;m_++) \
  _Pragma("unroll") for (int n_=0;n_<2;n_++) \
  _Pragma("unroll") for (int ks_=0;ks_<2;ks_++) \
    acc[QR][QC][m_][n_] = __builtin_amdgcn_mfma_f32_16x16x32_bf16(a[m_][ks_], breg[n_][ks_], acc[QR][QC][m_][n_], 0,0,0); }while(0)

__global__ __launch_bounds__(512) void k_ffn1(const unsigned short* __restrict__ xb,
                                              const unsigned short* __restrict__ w1b,
                                              const unsigned short* __restrict__ w3b,
                                              const int* __restrict__ counts,
                                              const int* __restrict__ entries,
                                              unsigned short* __restrict__ hidden){
  extern __shared__ unsigned short lds[];
  int flat = blockIdx.x;
  int nw = (flat & 7)*78 + (flat >> 3);     // 624 = 8*78 bijective XCD chunking
  int tile = nw % MAXT256;
  int nt   = nw / MAXT256;
  int e, ts_e, n_e, btot;
  EXPERT_PREFIX(tile, counts, e, ts_e, n_e, btot);
  if (tile >= btot) return;
  int row0 = (tile - ts_e)*256;
  int ebase = ts_e*256;

  int tid = threadIdx.x, lane = tid & 63, wid = tid >> 6;
  int wm = wid >> 2, wn = wid & 3;          // 2 x 4 wave grid

  const unsigned short* sA[2][2];
  const unsigned short* sB[2][2];
#pragma unroll
  for (int h=0;h<2;h++){
#pragma unroll
    for (int i=0;i<2;i++){
      int idx = i*512 + tid;
      int r = idx >> 3, seg = idx & 7;
      int sc = (seg ^ (r & 7))*8;
      int br = ((r>>6)<<7) | (h<<6) | (r & 63);   // interleaved A halves (bit6)
      int rr = row0 + br; rr = rr < n_e ? rr : (n_e - 1);
      int tokr = entries[ebase + rr] >> 1;
      sA[h][i] = xb + (size_t)tokr*H_DIM + sc;
      const unsigned short* w = h ? w3b : w1b;    // B part2=w1(gate), part3=w3(up)
      sB[h][i] = w + ((size_t)e*F_DIM + nt*128 + r)*H_DIM + sc;
    }
  }
  int dstb0 = wid*512;
  int dstb1 = 4096 + wid*512;

  int aoff[4][2], boff[2][2];
#pragma unroll
  for (int m=0;m<4;m++){
    int ia = wm*64 + m*16 + (lane & 15);
#pragma unroll
    for (int ks=0;ks<2;ks++)
      aoff[m][ks] = ia*128 + ((ks*64 + (lane>>4)*16) ^ ((ia & 7) << 4));
  }
#pragma unroll
  for (int n=0;n<2;n++){
    int ib = wn*32 + n*16 + (lane & 15);
#pragma unroll
    for (int ks=0;ks<2;ks++)
      boff[n][ks] = ib*128 + ((ks*64 + (lane>>4)*16) ^ ((ib & 7) << 4));
  }

  f32x4 acc[2][2][4][2];
#pragma unroll
  for (int qr=0;qr<2;qr++)
#pragma unroll
  for (int qc=0;qc<2;qc++)
#pragma unroll
  for (int m=0;m<4;m++)
#pragma unroll
  for (int n=0;n<2;n++) acc[qr][qc][m][n] = {0.f,0.f,0.f,0.f};

  bf16x8 a[4][2], bA[2][2], bB[2][2];

  // prologue: stage tile 0 in ledger order A0,B0,B1,A1
  STG(0, sA[0][0], sA[0][1], 0, 0);
  STG(2, sB[0][0], sB[0][1], 0, 0);
  STG(3, sB[1][0], sB[1][1], 0, 0);
  STG(1, sA[1][0], sA[1][1], 0, 0);

  for (int T=0; T<15; ++T){
    int db = T & 1, dbS = db ^ 1, kS = T + 1;
    // q0: needs A0,B0 (issued T-1 q0, 3 phases earlier)
    VMW(4); BARS;
    LDA(db,0); LDB(db,0,bA);
    STG(0, sA[0][0], sA[0][1], dbS, kS);
    STG(2, sB[0][0], sB[0][1], dbS, kS);
    MMGO; MM(0,0,bA); MMEND;
    // q1: needs B1 (issued T-1 q1, 3 phases earlier)
    VMW(6); BARS;
    LDB(db,1,bB);
    STG(3, sB[1][0], sB[1][1], dbS, kS);
    STG(1, sA[1][0], sA[1][1], dbS, kS);
    MMGO; MM(0,1,bB); MMEND;
    // q2+q3: needs A1 (issued T-1 q1); 32 MFMA
    VMW(8); BARS;
    LDA(db,1);
    MMGO; MM(1,0,bA); MM(1,1,bB); MMEND;
  }
  // epilogue tile 15 (db=1), no staging: drain 4 -> 2 -> 0
  VMW(4); BARS; LDA(1,0); LDB(1,0,bA); MMGO; MM(0,0,bA); MMEND;
  VMW(2); BARS; LDB(1,1,bB);           MMGO; MM(0,1,bB); MMEND;
  VMW(0); BARS; LDA(1,1);              MMGO; MM(1,0,bA); MM(1,1,bB); MMEND;

  // SiLU epilogue: gate=acc[qr][0], up=acc[qr][1]
  int r16 = ((lane >> 4) & 3)*4;
#pragma unroll
  for (int qr=0;qr<2;qr++){
#pragma unroll
    for (int m=0;m<4;m++){
#pragma unroll
      for (int j=0;j<4;j++){
        int br = wm*128 + qr*64 + m*16 + r16 + j;
        if (row0 + br < n_e){
          size_t rowbase = (size_t)(ebase + row0 + br)*F_DIM + nt*128 + wn*32;
#pragma unroll
          for (int n=0;n<2;n++){
            float g = acc[qr][0][m][n][j];
            float u = acc[qr][1][m][n][j];
            float h = (g / (1.f + __expf(-g))) * u;
            hidden[rowbase + n*16 + (lane & 15)] = f2bf(h);
          }
        }
      }
    }
  }
}

// ---------------- phase 2: 256x128 grouped GEMM + combine, K-split x2 -------
// Each block does 16 K-tiles (kh half of F). Grid 624 = 8 XCD x 78; combo =
// (nt, kh): nt == XCD -> w2 panel (4 MB) L2-resident. Triple-buffered LDS
// (3 x 48 KiB), stage 2 tiles ahead, VMW->BARS->reads (safe pattern).
// Parts: 0=A0, 1=A1, 2=B. Partial sums merged by fp32 atomicAdd (4/elem).

#define STG2(P, s0, s1, bufS, kS) do{ \
  GLD((s0) + (kS)*64, (bufS)*24576 + (P)*8192 + dstb0); \
  GLD((s1) + (kS)*64, (bufS)*24576 + (P)*8192 + dstb1); }while(0)

#define LDA2(buf, QR) do{ const char* p_ = (const char*)lds + (buf)*49152 + (QR)*16384; \
  _Pragma("unroll") for (int m_=0;m_<4;m_++) \
  _Pragma("unroll") for (int ks_=0;ks_<2;ks_++) \
    a[m_][ks_] = *(const bf16x8*)(p_ + aoff[m_][ks_]); }while(0)

#define LDB2(buf) do{ const char* p_ = (const char*)lds + (buf)*49152 + 32768; \
  _Pragma("unroll") for (int n_=0;n_<2;n_++) \
  _Pragma("unroll") for (int ks_=0;ks_<2;ks_++) \
    b[n_][ks_] = *(const bf16x8*)(p_ + boff[n_][ks_]); }while(0)

#define MM2(QR) do{ \
  _Pragma("unroll") for (int m_=0;m_<4;m_++) \
  _Pragma("unroll") for (int n_=0;n_<2;n_++) \
  _Pragma("unroll") for (int ks_=0;ks_<2;ks_++) \
    acc[QR][m_][n_] = __builtin_amdgcn_mfma_f32_16x16x32_bf16(a[m_][ks_], b[n_][ks_], acc[QR][m_][n_], 0,0,0); }while(0)

// one K-tile with staging (CUR compile-time, KT runtime)
#define F2T(CUR, ST, KT) do{ \
  VMW(6); BARS; \
  LDA2(CUR,0); LDB2(CUR); \
  STG2(0, sA[0][0], sA[0][1], ST, KT); \
  STG2(2, sB[0],    sB[1],    ST, KT); \
  MMGO; MM2(0); MMEND; BARS; \
  LDA2(CUR,1); \
  STG2(1, sA[1][0], sA[1][1], ST, KT); \
  MMGO; MM2(1); MMEND; }while(0)

__global__ __launch_bounds__(512) void k_ffn2(const unsigned short* __restrict__ hidden,
                                              const unsigned short* __restrict__ w2b,
                                              const int* __restrict__ counts,
                                              const int* __restrict__ entries,
                                              const float* __restrict__ topv,
                                              float* __restrict__ out){
  extern __shared__ unsigned short lds[];   // 3 * 24576 ushorts = 144 KiB
  int flat = blockIdx.x;
  int nw = (flat & 7)*78 + (flat >> 3);     // 624 = 8*78 bijective
  int tile  = nw % MAXT256;
  int combo = nw / MAXT256;                 // [0,16): XCD x gets combos 2x,2x+1
  int kh = combo & 1;
  int nt = combo >> 1;                      // nt == XCD index
  int kb = kh*16;                           // K-tile base (of 32)
  int e, ts_e, n_e, btot;
  EXPERT_PREFIX(tile, counts, e, ts_e, n_e, btot);
  if (tile >= btot) return;
  int row0 = (tile - ts_e)*256;
  int ebase = ts_e*256;

  int tid = threadIdx.x, lane = tid & 63, wid = tid >> 6;
  int wm = wid >> 2, wn = wid & 3;          // 2 x 4 wave grid

  const unsigned short* sA[2][2];
  const unsigned short* sB[2];
#pragma unroll
  for (int h=0;h<2;h++){
#pragma unroll
    for (int i=0;i<2;i++){
      int idx = i*512 + tid;
      int r = idx >> 3, seg = idx & 7;
      int sc = (seg ^ (r & 7))*8;
      int br = ((r>>6)<<7) | (h<<6) | (r & 63);
      sA[h][i] = hidden + (size_t)(ebase + row0 + br)*F_DIM + sc;  // padded rows: stale data, outputs discarded
    }
  }
#pragma unroll
  for (int i=0;i<2;i++){
    int idx = i*512 + tid;
    int r = idx >> 3, seg = idx & 7;
    int sc = (seg ^ (r & 7))*8;
    sB[i] = w2b + ((size_t)e*H_DIM + nt*128 + r)*F_DIM + sc;
  }
  int dstb0 = wid*512;
  int dstb1 = 4096 + wid*512;

  int aoff[4][2], boff[2][2];
#pragma unroll
  for (int m=0;m<4;m++){
    int ia = wm*64 + m*16 + (lane & 15);
#pragma unroll
    for (int ks=0;ks<2;ks++)
      aoff[m][ks] = ia*128 + ((ks*64 + (lane>>4)*16) ^ ((ia & 7) << 4));
  }
#pragma unroll
  for (int n=0;n<2;n++){
    int ib = wn*32 + n*16 + (lane & 15);
#pragma unroll
    for (int ks=0;ks<2;ks++)
      boff[n][ks] = ib*128 + ((ks*64 + (lane>>4)*16) ^ ((ib & 7) << 4));
  }

  f32x4 acc[2][4][2];
#pragma unroll
  for (int qr=0;qr<2;qr++)
#pragma unroll
  for (int m=0;m<4;m++)
#pragma unroll
  for (int n=0;n<2;n++) acc[qr][m][n] = {0.f,0.f,0.f,0.f};

  bf16x8 a[4][2], b[2][2];

  // prologue: stage K-tiles kb (buf0) and kb+1 (buf1)
  STG2(0, sA[0][0], sA[0][1], 0, kb);
  STG2(2, sB[0],    sB[1],    0, kb);
  STG2(1, sA[1][0], sA[1][1], 0, kb);
  STG2(0, sA[0][0], sA[0][1], 1, kb+1);
  STG2(2, sB[0],    sB[1],    1, kb+1);
  STG2(1, sA[1][0], sA[1][1], 1, kb+1);

  // T=0..11 (4 unrolled groups of 3), staging kb+2..kb+13
#pragma unroll 1
  for (int g=0; g<4; ++g){
    int k2 = kb + 3*g + 2;
    F2T(0, 2, k2);
    F2T(1, 0, k2+1);
    F2T(2, 1, k2+2);
  }
  F2T(0, 2, kb+14);   // T=12
  F2T(1, 0, kb+15);   // T=13
  // T=14: read buf2 (kb+14), no staging
  VMW(6); BARS; LDA2(2,0); LDB2(2); MMGO; MM2(0); MMEND; BARS;
  LDA2(2,1); MMGO; MM2(1); MMEND;
  // T=15: read buf0 (kb+15), drain
  VMW(0); BARS; LDA2(0,0); LDB2(0); MMGO; MM2(0); MMEND; BARS;
  LDA2(0,1); MMGO; MM2(1); MMEND;

  // weighted combine via fp32 atomics (each out elem gets 4 adds: 2 experts x 2 K-halves)
  int r16 = ((lane >> 4) & 3)*4;
#pragma unroll
  for (int qr=0;qr<2;qr++){
#pragma unroll
    for (int m=0;m<4;m++){
#pragma unroll
      for (int j=0;j<4;j++){
        int gr = row0 + wm*128 + qr*64 + m*16 + r16 + j;
        if (gr < n_e){
          int packed = entries[ebase + gr];
          int t = packed >> 1;
          float w = topv[packed];
#pragma unroll
          for (int n=0;n<2;n++){
            int col = nt*128 + wn*32 + n*16 + (lane & 15);
            atomicAdd(&out[(size_t)t*H_DIM + col], w * acc[qr][m][n][j]);
          }
        }
      }
    }
  }
}

// ---------------------------------------------------------------------------
extern "C" void kernel_launch(void* const* d_in, const int* in_sizes, int n_in,
                              void* d_out, int out_size, void* d_ws, size_t ws_size,
                              hipStream_t stream){
  const float* x  = (const float*)d_in[0];
  const float* rw = (const float*)d_in[1];
  const float* w1 = (const float*)d_in[2];
  const float* w2 = (const float*)d_in[3];
  const float* w3 = (const float*)d_in[4];
  float* out = (float*)d_out;

  char* ws = (char*)d_ws;
  size_t off = 0;
  unsigned short* xb  = (unsigned short*)(ws + off); off += (size_t)T_TOK*H_DIM*2;
  unsigned short* w1b = (unsigned short*)(ws + off); off += (size_t)E_NUM*F_DIM*H_DIM*2;
  unsigned short* w3b = (unsigned short*)(ws + off); off += (size_t)E_NUM*F_DIM*H_DIM*2;
  unsigned short* w2b = (unsigned short*)(ws + off); off += (size_t)E_NUM*H_DIM*F_DIM*2;
  unsigned short* hidden = (unsigned short*)(ws + off); off += (size_t)MAXROWS*F_DIM*2;
  int*   counts  = (int*)(ws + off); off += 64;   // [16] ints
  int*   cursors = (int*)(ws + off); off += 64;   // [16] ints (counts+cursors = zbase[32])
  int*   topi    = (int*)(ws + off); off += (size_t)T_TOK*2*4;
  float* topv    = (float*)(ws + off); off += (size_t)T_TOK*2*4;
  int*   entries = (int*)(ws + off); off += (size_t)MAXROWS*4;

  hipFuncSetAttribute((const void*)k_ffn1,
                      hipFuncAttributeMaxDynamicSharedMemorySize, 131072);
  hipFuncSetAttribute((const void*)k_ffn2,
                      hipFuncAttributeMaxDynamicSharedMemorySize, 147456);

  k_wcvt<<<3*2048, 256, 0, stream>>>(w1, w3, w2, w1b, w3b, w2b, out, counts);
  k_router<<<T_TOK/32, 256, 0, stream>>>(x, rw, counts, topi, topv, xb);
  k_fill<<<T_TOK/256, 256, 0, stream>>>(topi, counts, cursors, entries);
  k_ffn1<<<MAXT256*16, 512, 131072, stream>>>(xb, w1b, w3b, counts, entries, hidden);
  k_ffn2<<<MAXT256*16, 512, 147456, stream>>>(hidden, w2b, counts, entries, topv, out);
}

// Round 7
// 306.353 us; speedup vs baseline: 1.0874x; 1.0642x over previous
//
#include <hip/hip_runtime.h>
#include <hip/hip_bf16.h>
#include <cstdint>

#define T_TOK 4096
#define H_DIM 1024
#define F_DIM 2048
#define E_NUM 8
#define MAXT256 39
#define MAXROWS (MAXT256*256)   // 9984 padded entry rows

typedef __attribute__((ext_vector_type(8))) short bf16x8;
typedef __attribute__((ext_vector_type(4))) float f32x4;

__device__ __forceinline__ unsigned short f2bf(float f){
  union { float f; uint32_t u; } c; c.f = f;
  uint32_t u = c.u;
  uint32_t r = (u + 0x7fffu + ((u >> 16) & 1u)) >> 16;
  return (unsigned short)r;
}

// expert lookup from counts via unrolled prefix (no k_offsets kernel needed)
#define EXPERT_PREFIX(tile, counts, e, ts_e, n_e, btot) do{ \
  btot = 0; e = 0; ts_e = 0; n_e = 0; \
  _Pragma("unroll") for (int i_=0;i_<E_NUM;i_++){ \
    int cnt_ = (counts)[i_]; \
    if ((tile) >= btot){ e = i_; ts_e = btot; n_e = cnt_; } \
    btot += (cnt_ + 255) >> 8; } }while(0)

// ---- weights fp32 -> bf16 (3 segments) + zero counts/cursors + zero out ----
__global__ __launch_bounds__(256) void k_wcvt(const float* __restrict__ w1,
                                              const float* __restrict__ w3,
                                              const float* __restrict__ w2,
                                              unsigned short* __restrict__ w1b,
                                              unsigned short* __restrict__ w3b,
                                              unsigned short* __restrict__ w2b,
                                              float* __restrict__ out,
                                              int* __restrict__ zbase){
  int tid = threadIdx.x;
  if (blockIdx.x == 0 && tid < 32) zbase[tid] = 0;   // counts[16] + cursors[16]
  float4 z4 = {0.f,0.f,0.f,0.f};
  for (int i = blockIdx.x*256 + tid; i < T_TOK*H_DIM/4; i += 6144*256)
    reinterpret_cast<float4*>(out)[i] = z4;
  int seg = blockIdx.x >> 11;
  int b   = blockIdx.x & 2047;
  const float* s = seg==0 ? w1 : (seg==1 ? w3 : w2);
  unsigned short* d = seg==0 ? w1b : (seg==1 ? w3b : w2b);
  const int n4 = E_NUM*F_DIM*H_DIM/4;
  for (int i = b*256 + tid; i < n4; i += 2048*256){
    float4 v = reinterpret_cast<const float4*>(s)[i];
    ushort4 o;
    o.x = f2bf(v.x); o.y = f2bf(v.y); o.z = f2bf(v.z); o.w = f2bf(v.w);
    reinterpret_cast<ushort4*>(d)[i] = o;
  }
}

// ------- router: 32 tokens/block, 8 lanes/token, rw staged in LDS -----------
__global__ __launch_bounds__(256) void k_router(const float* __restrict__ x,
                                               const float* __restrict__ rw,
                                               int* __restrict__ counts,
                                               int* __restrict__ topi,
                                               float* __restrict__ topv,
                                               unsigned short* __restrict__ xb){
  __shared__ float lrw[E_NUM][8][132];
  __shared__ int hist[E_NUM];
  int tid = threadIdx.x;
  if (tid < E_NUM) hist[tid] = 0;
  for (int i = tid; i < E_NUM*H_DIM/4; i += 256){
    int idx = i*4;
    int e = idx >> 10, rem = idx & 1023, c = rem >> 7, j = rem & 127;
    float4 v = reinterpret_cast<const float4*>(rw)[i];
    *reinterpret_cast<float4*>(&lrw[e][c][j]) = v;
  }
  __syncthreads();

  int t = blockIdx.x*32 + (tid >> 3);
  int c = tid & 7;
  const float4* xr = reinterpret_cast<const float4*>(x + (size_t)t*H_DIM + c*128);
  ushort4* xw = reinterpret_cast<ushort4*>(xb + (size_t)t*H_DIM + c*128);
  double acc[E_NUM];
#pragma unroll
  for (int e=0;e<E_NUM;e++) acc[e] = 0.0;
  for (int j4=0; j4<32; ++j4){
    float4 v = xr[j4];
    ushort4 o;
    o.x = f2bf(v.x); o.y = f2bf(v.y); o.z = f2bf(v.z); o.w = f2bf(v.w);
    xw[j4] = o;
#pragma unroll
    for (int e=0;e<E_NUM;e++){
      float4 r = *reinterpret_cast<const float4*>(&lrw[e][c][j4*4]);
      acc[e] += (double)v.x*(double)r.x + (double)v.y*(double)r.y
              + (double)v.z*(double)r.z + (double)v.w*(double)r.w;
    }
  }
#pragma unroll
  for (int e=0;e<E_NUM;e++){
    double s = acc[e];
    s += __shfl_xor(s, 1, 64);
    s += __shfl_xor(s, 2, 64);
    s += __shfl_xor(s, 4, 64);
    acc[e] = s;
  }
  if (c == 0){
    int i0 = 0; double v0 = acc[0];
    for (int e=1;e<E_NUM;e++) if (acc[e] > v0){ v0 = acc[e]; i0 = e; }
    int i1 = -1; double v1 = -1e300;
    for (int e=0;e<E_NUM;e++) if (e != i0 && acc[e] > v1){ v1 = acc[e]; i1 = e; }
    float w0 = 1.0f/(1.0f + expf((float)(v1 - v0)));
    topi[2*t] = i0; topi[2*t+1] = i1;
    topv[2*t] = w0; topv[2*t+1] = 1.0f - w0;
    atomicAdd(&hist[i0], 1); atomicAdd(&hist[i1], 1);
  }
  __syncthreads();
  if (tid < E_NUM && hist[tid]) atomicAdd(&counts[tid], hist[tid]);
}

// ---------------- fill grouped entry lists (prefix computed locally) --------
__global__ __launch_bounds__(256) void k_fill(const int* __restrict__ topi,
                                              const int* __restrict__ counts,
                                              int* __restrict__ cursors,
                                              int* __restrict__ entries){
  __shared__ int ts[E_NUM];
  if (threadIdx.x == 0){
    int b = 0;
    for (int e=0;e<E_NUM;e++){ ts[e] = b; b += (counts[e] + 255) >> 8; }
  }
  __syncthreads();
  int t = blockIdx.x*256 + threadIdx.x;
  if (t >= T_TOK) return;
#pragma unroll
  for (int k=0;k<2;k++){
    int e = topi[2*t+k];
    int pos = atomicAdd(&cursors[e], 1);
    entries[ts[e]*256 + pos] = 2*t + k;
  }
}

// ---------------- shared sync / staging macros ------------------------------
#define GLD(src, dst_us) __builtin_amdgcn_global_load_lds( \
  (const __attribute__((address_space(1))) unsigned int*)(src), \
  (__attribute__((address_space(3))) unsigned int*)(lds + (dst_us)), 16, 0, 0)

#define VMW(N) asm volatile("s_waitcnt vmcnt(" #N ")" ::: "memory")
#define BARS do{ __builtin_amdgcn_s_barrier(); __builtin_amdgcn_sched_barrier(0); }while(0)
#define MMGO do{ asm volatile("s_waitcnt lgkmcnt(0)" ::: "memory"); \
  __builtin_amdgcn_sched_barrier(0); __builtin_amdgcn_s_setprio(1); }while(0)
#define MMEND __builtin_amdgcn_s_setprio(0)

// ---------------- 256x256 3-phase K-loop macros (shared by ffn1/ffn2) -------
// Parts per 64KiB buffer: 0=A0, 1=A1, 2=B0, 3=B1. 3 phases/K-tile,
// VMW(4)/VMW(6)/VMW(8), one barrier per phase, stage into the other dbuf.

#define STG(X, s0, s1, dbS, kS) do{ \
  GLD((s0) + (kS)*64, (dbS)*32768 + (X)*8192 + dstb0); \
  GLD((s1) + (kS)*64, (dbS)*32768 + (X)*8192 + dstb1); }while(0)

#define LDA(db, QR) do{ const char* p_ = (const char*)lds + ((db)*4 + (QR))*16384; \
  _Pragma("unroll") for (int m_=0;m_<4;m_++) \
  _Pragma("unroll") for (int ks_=0;ks_<2;ks_++) \
    a[m_][ks_] = *(const bf16x8*)(p_ + aoff[m_][ks_]); }while(0)

#define LDB(db, QC, breg) do{ const char* p_ = (const char*)lds + ((db)*4 + 2 + (QC))*16384; \
  _Pragma("unroll") for (int n_=0;n_<2;n_++) \
  _Pragma("unroll") for (int ks_=0;ks_<2;ks_++) \
    breg[n_][ks_] = *(const bf16x8*)(p_ + boff[n_][ks_]); }while(0)

#define MM(QR, QC, breg) do{ \
  _Pragma("unroll") for (int m_=0;m_<4;m_++) \
  _Pragma("unroll") for (int n_=0;n_<2;n_++) \
  _Pragma("unroll") for (int ks_=0;ks_<2;ks_++) \
    acc[QR][QC][m_][n_] = __builtin_amdgcn_mfma_f32_16x16x32_bf16(a[m_][ks_], breg[n_][ks_], acc[QR][QC][m_][n_], 0,0,0); }while(0)

// 16-K-tile double-buffered main loop + drain epilogue (kb = K-tile base)
#define KLOOP16(kb) do{ \
  STG(0, sA[0][0], sA[0][1], 0, (kb)); \
  STG(2, sB[0][0], sB[0][1], 0, (kb)); \
  STG(3, sB[1][0], sB[1][1], 0, (kb)); \
  STG(1, sA[1][0], sA[1][1], 0, (kb)); \
  for (int T=0; T<15; ++T){ \
    int db = T & 1, dbS = db ^ 1, kS = (kb) + T + 1; \
    VMW(4); BARS; \
    if (db == 0){ LDA(0,0); LDB(0,0,bA); } else { LDA(1,0); LDB(1,0,bA); } \
    STG(0, sA[0][0], sA[0][1], dbS, kS); \
    STG(2, sB[0][0], sB[0][1], dbS, kS); \
    MMGO; MM(0,0,bA); MMEND; \
    VMW(6); BARS; \
    if (db == 0){ LDB(0,1,bB); } else { LDB(1,1,bB); } \
    STG(3, sB[1][0], sB[1][1], dbS, kS); \
    STG(1, sA[1][0], sA[1][1], dbS, kS); \
    MMGO; MM(0,1,bB); MMEND; \
    VMW(8); BARS; \
    if (db == 0){ LDA(0,1); } else { LDA(1,1); } \
    MMGO; MM(1,0,bA); MM(1,1,bB); MMEND; \
  } \
  VMW(4); BARS; LDA(1,0); LDB(1,0,bA); MMGO; MM(0,0,bA); MMEND; \
  VMW(2); BARS; LDB(1,1,bB);           MMGO; MM(0,1,bB); MMEND; \
  VMW(0); BARS; LDA(1,1);              MMGO; MM(1,0,bA); MM(1,1,bB); MMEND; }while(0)

// ---------------- phase 1: 256x256 grouped GEMM + SiLU ----------------------
__global__ __launch_bounds__(512) void k_ffn1(const unsigned short* __restrict__ xb,
                                              const unsigned short* __restrict__ w1b,
                                              const unsigned short* __restrict__ w3b,
                                              const int* __restrict__ counts,
                                              const int* __restrict__ entries,
                                              unsigned short* __restrict__ hidden){
  extern __shared__ unsigned short lds[];
  int flat = blockIdx.x;
  int nw = (flat & 7)*78 + (flat >> 3);     // 624 = 8*78 bijective XCD chunking
  int tile = nw % MAXT256;
  int nt   = nw / MAXT256;
  int e, ts_e, n_e, btot;
  EXPERT_PREFIX(tile, counts, e, ts_e, n_e, btot);
  if (tile >= btot) return;
  int row0 = (tile - ts_e)*256;
  int ebase = ts_e*256;

  int tid = threadIdx.x, lane = tid & 63, wid = tid >> 6;
  int wm = wid >> 2, wn = wid & 3;          // 2 x 4 wave grid

  const unsigned short* sA[2][2];
  const unsigned short* sB[2][2];
#pragma unroll
  for (int h=0;h<2;h++){
#pragma unroll
    for (int i=0;i<2;i++){
      int idx = i*512 + tid;
      int r = idx >> 3, seg = idx & 7;
      int sc = (seg ^ (r & 7))*8;
      int br = ((r>>6)<<7) | (h<<6) | (r & 63);   // interleaved A halves (bit6)
      int rr = row0 + br; rr = rr < n_e ? rr : (n_e - 1);
      int tokr = entries[ebase + rr] >> 1;
      sA[h][i] = xb + (size_t)tokr*H_DIM + sc;
      const unsigned short* w = h ? w3b : w1b;    // B part2=w1(gate), part3=w3(up)
      sB[h][i] = w + ((size_t)e*F_DIM + nt*128 + r)*H_DIM + sc;
    }
  }
  int dstb0 = wid*512;
  int dstb1 = 4096 + wid*512;

  int aoff[4][2], boff[2][2];
#pragma unroll
  for (int m=0;m<4;m++){
    int ia = wm*64 + m*16 + (lane & 15);
#pragma unroll
    for (int ks=0;ks<2;ks++)
      aoff[m][ks] = ia*128 + ((ks*64 + (lane>>4)*16) ^ ((ia & 7) << 4));
  }
#pragma unroll
  for (int n=0;n<2;n++){
    int ib = wn*32 + n*16 + (lane & 15);
#pragma unroll
    for (int ks=0;ks<2;ks++)
      boff[n][ks] = ib*128 + ((ks*64 + (lane>>4)*16) ^ ((ib & 7) << 4));
  }

  f32x4 acc[2][2][4][2];
#pragma unroll
  for (int qr=0;qr<2;qr++)
#pragma unroll
  for (int qc=0;qc<2;qc++)
#pragma unroll
  for (int m=0;m<4;m++)
#pragma unroll
  for (int n=0;n<2;n++) acc[qr][qc][m][n] = {0.f,0.f,0.f,0.f};

  bf16x8 a[4][2], bA[2][2], bB[2][2];

  KLOOP16(0);

  // SiLU epilogue: gate=acc[qr][0], up=acc[qr][1]
  int r16 = ((lane >> 4) & 3)*4;
#pragma unroll
  for (int qr=0;qr<2;qr++){
#pragma unroll
    for (int m=0;m<4;m++){
#pragma unroll
      for (int j=0;j<4;j++){
        int br = wm*128 + qr*64 + m*16 + r16 + j;
        if (row0 + br < n_e){
          size_t rowbase = (size_t)(ebase + row0 + br)*F_DIM + nt*128 + wn*32;
#pragma unroll
          for (int n=0;n<2;n++){
            float g = acc[qr][0][m][n][j];
            float u = acc[qr][1][m][n][j];
            float h = (g / (1.f + __expf(-g))) * u;
            hidden[rowbase + n*16 + (lane & 15)] = f2bf(h);
          }
        }
      }
    }
  }
}

// ---------------- phase 2: 256x256 grouped GEMM + combine (ffn1 clone) ------
// A = 256 hidden rows (contiguous, bit6-interleaved halves), B0/B1 = w2 rows
// nt*256..+256 (K-stride F_DIM), kh in {0,1} K-half (16 K-tiles each).
// Grid 312 = 8 XCD x 39: combo (nt,kh) == XCD -> w2 slice 4 MB = its L2.
// Same 128 KiB dbuf LDS + byte-identical 3-phase vmcnt ledger as k_ffn1.
// Partials merged by fp32 atomicAdd (4 adds/elem: 2 experts x 2 K-halves).
__global__ __launch_bounds__(512) void k_ffn2(const unsigned short* __restrict__ hidden,
                                              const unsigned short* __restrict__ w2b,
                                              const int* __restrict__ counts,
                                              const int* __restrict__ entries,
                                              const float* __restrict__ topv,
                                              float* __restrict__ out){
  extern __shared__ unsigned short lds[];
  int flat = blockIdx.x;
  int nw = (flat & 7)*39 + (flat >> 3);     // 312 = 8*39 bijective
  int tile  = nw % MAXT256;
  int combo = nw / MAXT256;                 // == XCD id, in [0,8)
  int nt = combo & 3;                       // 256-col group of H
  int kh = combo >> 2;                      // K half of F
  int kb = kh*16;                           // K-tile base
  int e, ts_e, n_e, btot;
  EXPERT_PREFIX(tile, counts, e, ts_e, n_e, btot);
  if (tile >= btot) return;
  int row0 = (tile - ts_e)*256;
  int ebase = ts_e*256;

  int tid = threadIdx.x, lane = tid & 63, wid = tid >> 6;
  int wm = wid >> 2, wn = wid & 3;          // 2 x 4 wave grid

  const unsigned short* sA[2][2];
  const unsigned short* sB[2][2];
#pragma unroll
  for (int h=0;h<2;h++){
#pragma unroll
    for (int i=0;i<2;i++){
      int idx = i*512 + tid;
      int r = idx >> 3, seg = idx & 7;
      int sc = (seg ^ (r & 7))*8;
      int br = ((r>>6)<<7) | (h<<6) | (r & 63);   // interleaved A halves (bit6)
      sA[h][i] = hidden + (size_t)(ebase + row0 + br)*F_DIM + sc;  // padded rows: stale data, discarded
      sB[h][i] = w2b + ((size_t)e*H_DIM + nt*256 + h*128 + r)*F_DIM + sc;
    }
  }
  int dstb0 = wid*512;
  int dstb1 = 4096 + wid*512;

  int aoff[4][2], boff[2][2];
#pragma unroll
  for (int m=0;m<4;m++){
    int ia = wm*64 + m*16 + (lane & 15);
#pragma unroll
    for (int ks=0;ks<2;ks++)
      aoff[m][ks] = ia*128 + ((ks*64 + (lane>>4)*16) ^ ((ia & 7) << 4));
  }
#pragma unroll
  for (int n=0;n<2;n++){
    int ib = wn*32 + n*16 + (lane & 15);
#pragma unroll
    for (int ks=0;ks<2;ks++)
      boff[n][ks] = ib*128 + ((ks*64 + (lane>>4)*16) ^ ((ib & 7) << 4));
  }

  f32x4 acc[2][2][4][2];
#pragma unroll
  for (int qr=0;qr<2;qr++)
#pragma unroll
  for (int qc=0;qc<2;qc++)
#pragma unroll
  for (int m=0;m<4;m++)
#pragma unroll
  for (int n=0;n<2;n++) acc[qr][qc][m][n] = {0.f,0.f,0.f,0.f};

  bf16x8 a[4][2], bA[2][2], bB[2][2];

  KLOOP16(kb);

  // weighted combine: acc[qr][qc] -> out cols nt*256 + qc*128 + wn*32 + ...
  int r16 = ((lane >> 4) & 3)*4;
#pragma unroll
  for (int qr=0;qr<2;qr++){
#pragma unroll
    for (int m=0;m<4;m++){
#pragma unroll
      for (int j=0;j<4;j++){
        int gr = row0 + wm*128 + qr*64 + m*16 + r16 + j;
        if (gr < n_e){
          int packed = entries[ebase + gr];
          int t = packed >> 1;
          float w = topv[packed];
#pragma unroll
          for (int qc=0;qc<2;qc++){
#pragma unroll
            for (int n=0;n<2;n++){
              int col = nt*256 + qc*128 + wn*32 + n*16 + (lane & 15);
              atomicAdd(&out[(size_t)t*H_DIM + col], w * acc[qr][qc][m][n][j]);
            }
          }
        }
      }
    }
  }
}

// ---------------------------------------------------------------------------
extern "C" void kernel_launch(void* const* d_in, const int* in_sizes, int n_in,
                              void* d_out, int out_size, void* d_ws, size_t ws_size,
                              hipStream_t stream){
  const float* x  = (const float*)d_in[0];
  const float* rw = (const float*)d_in[1];
  const float* w1 = (const float*)d_in[2];
  const float* w2 = (const float*)d_in[3];
  const float* w3 = (const float*)d_in[4];
  float* out = (float*)d_out;

  char* ws = (char*)d_ws;
  size_t off = 0;
  unsigned short* xb  = (unsigned short*)(ws + off); off += (size_t)T_TOK*H_DIM*2;
  unsigned short* w1b = (unsigned short*)(ws + off); off += (size_t)E_NUM*F_DIM*H_DIM*2;
  unsigned short* w3b = (unsigned short*)(ws + off); off += (size_t)E_NUM*F_DIM*H_DIM*2;
  unsigned short* w2b = (unsigned short*)(ws + off); off += (size_t)E_NUM*H_DIM*F_DIM*2;
  unsigned short* hidden = (unsigned short*)(ws + off); off += (size_t)MAXROWS*F_DIM*2;
  int*   counts  = (int*)(ws + off); off += 64;   // [16] ints
  int*   cursors = (int*)(ws + off); off += 64;   // [16] ints (counts+cursors = zbase[32])
  int*   topi    = (int*)(ws + off); off += (size_t)T_TOK*2*4;
  float* topv    = (float*)(ws + off); off += (size_t)T_TOK*2*4;
  int*   entries = (int*)(ws + off); off += (size_t)MAXROWS*4;

  hipFuncSetAttribute((const void*)k_ffn1,
                      hipFuncAttributeMaxDynamicSharedMemorySize, 131072);
  hipFuncSetAttribute((const void*)k_ffn2,
                      hipFuncAttributeMaxDynamicSharedMemorySize, 131072);

  k_wcvt<<<3*2048, 256, 0, stream>>>(w1, w3, w2, w1b, w3b, w2b, out, counts);
  k_router<<<T_TOK/32, 256, 0, stream>>>(x, rw, counts, topi, topv, xb);
  k_fill<<<T_TOK/256, 256, 0, stream>>>(topi, counts, cursors, entries);
  k_ffn1<<<MAXT256*16, 512, 131072, stream>>>(xb, w1b, w3b, counts, entries, hidden);
  k_ffn2<<<MAXT256*8, 512, 131072, stream>>>(hidden, w2b, counts, entries, topv, out);
}

// Round 8
// 300.715 us; speedup vs baseline: 1.1078x; 1.0187x over previous
//
#include <hip/hip_runtime.h>
#include <hip/hip_bf16.h>
#include <cstdint>

#define T_TOK 4096
#define H_DIM 1024
#define F_DIM 2048
#define E_NUM 8
#define MAXT256 39
#define MAXROWS (MAXT256*256)   // 9984 padded entry rows

typedef __attribute__((ext_vector_type(8))) short bf16x8;
typedef __attribute__((ext_vector_type(4))) float f32x4;

__device__ __forceinline__ unsigned short f2bf(float f){
  union { float f; uint32_t u; } c; c.f = f;
  uint32_t u = c.u;
  uint32_t r = (u + 0x7fffu + ((u >> 16) & 1u)) >> 16;
  return (unsigned short)r;
}

// expert lookup from counts via unrolled prefix (no k_offsets kernel needed)
#define EXPERT_PREFIX(tile, counts, e, ts_e, n_e, btot) do{ \
  btot = 0; e = 0; ts_e = 0; n_e = 0; \
  _Pragma("unroll") for (int i_=0;i_<E_NUM;i_++){ \
    int cnt_ = (counts)[i_]; \
    if ((tile) >= btot){ e = i_; ts_e = btot; n_e = cnt_; } \
    btot += (cnt_ + 255) >> 8; } }while(0)

// ---- weights fp32 -> bf16 (3 segments) + zero counts/cursors + zero out ----
__global__ __launch_bounds__(256) void k_wcvt(const float* __restrict__ w1,
                                              const float* __restrict__ w3,
                                              const float* __restrict__ w2,
                                              unsigned short* __restrict__ w1b,
                                              unsigned short* __restrict__ w3b,
                                              unsigned short* __restrict__ w2b,
                                              float* __restrict__ out,
                                              int* __restrict__ zbase){
  int tid = threadIdx.x;
  if (blockIdx.x == 0 && tid < 32) zbase[tid] = 0;   // counts[16] + cursors[16]
  float4 z4 = {0.f,0.f,0.f,0.f};
  for (int i = blockIdx.x*256 + tid; i < T_TOK*H_DIM/4; i += 6144*256)
    reinterpret_cast<float4*>(out)[i] = z4;
  int seg = blockIdx.x >> 11;
  int b   = blockIdx.x & 2047;
  const float* s = seg==0 ? w1 : (seg==1 ? w3 : w2);
  unsigned short* d = seg==0 ? w1b : (seg==1 ? w3b : w2b);
  const int n4 = E_NUM*F_DIM*H_DIM/4;
  for (int i = b*256 + tid; i < n4; i += 2048*256){
    float4 v = reinterpret_cast<const float4*>(s)[i];
    ushort4 o;
    o.x = f2bf(v.x); o.y = f2bf(v.y); o.z = f2bf(v.z); o.w = f2bf(v.w);
    reinterpret_cast<ushort4*>(d)[i] = o;
  }
}

// ------- router: 32 tokens/block, 8 lanes/token, rw staged in LDS -----------
__global__ __launch_bounds__(256) void k_router(const float* __restrict__ x,
                                               const float* __restrict__ rw,
                                               int* __restrict__ counts,
                                               int* __restrict__ topi,
                                               float* __restrict__ topv,
                                               unsigned short* __restrict__ xb){
  __shared__ float lrw[E_NUM][8][132];
  __shared__ int hist[E_NUM];
  int tid = threadIdx.x;
  if (tid < E_NUM) hist[tid] = 0;
  for (int i = tid; i < E_NUM*H_DIM/4; i += 256){
    int idx = i*4;
    int e = idx >> 10, rem = idx & 1023, c = rem >> 7, j = rem & 127;
    float4 v = reinterpret_cast<const float4*>(rw)[i];
    *reinterpret_cast<float4*>(&lrw[e][c][j]) = v;
  }
  __syncthreads();

  int t = blockIdx.x*32 + (tid >> 3);
  int c = tid & 7;
  const float4* xr = reinterpret_cast<const float4*>(x + (size_t)t*H_DIM + c*128);
  ushort4* xw = reinterpret_cast<ushort4*>(xb + (size_t)t*H_DIM + c*128);
  double acc[E_NUM];
#pragma unroll
  for (int e=0;e<E_NUM;e++) acc[e] = 0.0;
  for (int j4=0; j4<32; ++j4){
    float4 v = xr[j4];
    ushort4 o;
    o.x = f2bf(v.x); o.y = f2bf(v.y); o.z = f2bf(v.z); o.w = f2bf(v.w);
    xw[j4] = o;
#pragma unroll
    for (int e=0;e<E_NUM;e++){
      float4 r = *reinterpret_cast<const float4*>(&lrw[e][c][j4*4]);
      acc[e] += (double)v.x*(double)r.x + (double)v.y*(double)r.y
              + (double)v.z*(double)r.z + (double)v.w*(double)r.w;
    }
  }
#pragma unroll
  for (int e=0;e<E_NUM;e++){
    double s = acc[e];
    s += __shfl_xor(s, 1, 64);
    s += __shfl_xor(s, 2, 64);
    s += __shfl_xor(s, 4, 64);
    acc[e] = s;
  }
  if (c == 0){
    int i0 = 0; double v0 = acc[0];
    for (int e=1;e<E_NUM;e++) if (acc[e] > v0){ v0 = acc[e]; i0 = e; }
    int i1 = -1; double v1 = -1e300;
    for (int e=0;e<E_NUM;e++) if (e != i0 && acc[e] > v1){ v1 = acc[e]; i1 = e; }
    float w0 = 1.0f/(1.0f + expf((float)(v1 - v0)));
    topi[2*t] = i0; topi[2*t+1] = i1;
    topv[2*t] = w0; topv[2*t+1] = 1.0f - w0;
    atomicAdd(&hist[i0], 1); atomicAdd(&hist[i1], 1);
  }
  __syncthreads();
  if (tid < E_NUM && hist[tid]) atomicAdd(&counts[tid], hist[tid]);
}

// ---------------- fill grouped entry lists (prefix computed locally) --------
__global__ __launch_bounds__(256) void k_fill(const int* __restrict__ topi,
                                              const int* __restrict__ counts,
                                              int* __restrict__ cursors,
                                              int* __restrict__ entries){
  __shared__ int ts[E_NUM];
  if (threadIdx.x == 0){
    int b = 0;
    for (int e=0;e<E_NUM;e++){ ts[e] = b; b += (counts[e] + 255) >> 8; }
  }
  __syncthreads();
  int t = blockIdx.x*256 + threadIdx.x;
  if (t >= T_TOK) return;
#pragma unroll
  for (int k=0;k<2;k++){
    int e = topi[2*t+k];
    int pos = atomicAdd(&cursors[e], 1);
    entries[ts[e]*256 + pos] = 2*t + k;
  }
}

// ---------------- shared sync / staging macros ------------------------------
#define GLD(src, dst_us) __builtin_amdgcn_global_load_lds( \
  (const __attribute__((address_space(1))) unsigned int*)(src), \
  (__attribute__((address_space(3))) unsigned int*)(lds + (dst_us)), 16, 0, 0)

#define VMW(N) asm volatile("s_waitcnt vmcnt(" #N ")" ::: "memory")
#define BARS do{ __builtin_amdgcn_s_barrier(); __builtin_amdgcn_sched_barrier(0); }while(0)
#define MMGO do{ asm volatile("s_waitcnt lgkmcnt(0)" ::: "memory"); \
  __builtin_amdgcn_sched_barrier(0); __builtin_amdgcn_s_setprio(1); }while(0)
#define MMEND __builtin_amdgcn_s_setprio(0)

// ---------------- 256x256 fused K-loop (shared by ffn1/ffn2) ----------------
// Parts per 64KiB buffer: 0=A0, 1=A1, 2=B0, 3=B1. ONE phase per K-tile:
// VMW(0) waits the 8 staging loads issued one full K-tile earlier (~2500cy
// distance >> HBM latency). Barrier-protected overwrite: each wave's
// lgkmcnt(0) precedes its MFMAs which precede the barrier, so all reads of
// the buffer being overwritten completed before staging starts.

#define STG(X, s0, s1, dbS, kS) do{ \
  GLD((s0) + (kS)*64, (dbS)*32768 + (X)*8192 + dstb0); \
  GLD((s1) + (kS)*64, (dbS)*32768 + (X)*8192 + dstb1); }while(0)

#define LDA(db, QR) do{ const char* p_ = (const char*)lds + ((db)*4 + (QR))*16384; \
  _Pragma("unroll") for (int m_=0;m_<4;m_++) \
  _Pragma("unroll") for (int ks_=0;ks_<2;ks_++) \
    a[m_][ks_] = *(const bf16x8*)(p_ + aoff[m_][ks_]); }while(0)

#define LDB(db, QC, breg) do{ const char* p_ = (const char*)lds + ((db)*4 + 2 + (QC))*16384; \
  _Pragma("unroll") for (int n_=0;n_<2;n_++) \
  _Pragma("unroll") for (int ks_=0;ks_<2;ks_++) \
    breg[n_][ks_] = *(const bf16x8*)(p_ + boff[n_][ks_]); }while(0)

#define MM(QR, QC, breg) do{ \
  _Pragma("unroll") for (int m_=0;m_<4;m_++) \
  _Pragma("unroll") for (int n_=0;n_<2;n_++) \
  _Pragma("unroll") for (int ks_=0;ks_<2;ks_++) \
    acc[QR][QC][m_][n_] = __builtin_amdgcn_mfma_f32_16x16x32_bf16(a[m_][ks_], breg[n_][ks_], acc[QR][QC][m_][n_], 0,0,0); }while(0)

// one fused K-tile: read buffer db, stage K-tile kS into db^1 (if STG_ON)
#define KSTEP(db, STG_ON, kS) do{ \
  VMW(0); BARS; \
  if (STG_ON){ \
    STG(0, sA[0][0], sA[0][1], (db)^1, (kS)); \
    STG(2, sB[0][0], sB[0][1], (db)^1, (kS)); \
    STG(3, sB[1][0], sB[1][1], (db)^1, (kS)); \
    STG(1, sA[1][0], sA[1][1], (db)^1, (kS)); \
  } \
  LDA(db,0); LDB(db,0,bA); LDB(db,1,bB); \
  MMGO; MM(0,0,bA); MM(0,1,bB); MMEND; \
  LDA(db,1); \
  MMGO; MM(1,0,bA); MM(1,1,bB); MMEND; \
}while(0)

#define KPRO(kb) do{ \
  STG(0, sA[0][0], sA[0][1], 0, (kb)); \
  STG(2, sB[0][0], sB[0][1], 0, (kb)); \
  STG(3, sB[1][0], sB[1][1], 0, (kb)); \
  STG(1, sA[1][0], sA[1][1], 0, (kb)); }while(0)

#define KLOOP16F() do{ \
  KPRO(0); \
  _Pragma("unroll 1") for (int tt=0; tt<7; ++tt){ \
    KSTEP(0, 1, 2*tt+1); \
    KSTEP(1, 1, 2*tt+2); \
  } \
  KSTEP(0, 1, 15); \
  KSTEP(1, 0, 0); \
}while(0)

#define KLOOP32F() do{ \
  KPRO(0); \
  _Pragma("unroll 1") for (int tt=0; tt<15; ++tt){ \
    KSTEP(0, 1, 2*tt+1); \
    KSTEP(1, 1, 2*tt+2); \
  } \
  KSTEP(0, 1, 31); \
  KSTEP(1, 0, 0); \
}while(0)

// ---------------- phase 1: 256x256 grouped GEMM + SiLU ----------------------
__global__ __launch_bounds__(512) void k_ffn1(const unsigned short* __restrict__ xb,
                                              const unsigned short* __restrict__ w1b,
                                              const unsigned short* __restrict__ w3b,
                                              const int* __restrict__ counts,
                                              const int* __restrict__ entries,
                                              unsigned short* __restrict__ hidden){
  extern __shared__ unsigned short lds[];
  int flat = blockIdx.x;
  int nw = (flat & 7)*78 + (flat >> 3);     // 624 = 8*78 bijective XCD chunking
  int tile = nw % MAXT256;
  int nt   = nw / MAXT256;
  int e, ts_e, n_e, btot;
  EXPERT_PREFIX(tile, counts, e, ts_e, n_e, btot);
  if (tile >= btot) return;
  int row0 = (tile - ts_e)*256;
  int ebase = ts_e*256;

  int tid = threadIdx.x, lane = tid & 63, wid = tid >> 6;
  int wm = wid >> 2, wn = wid & 3;          // 2 x 4 wave grid

  const unsigned short* sA[2][2];
  const unsigned short* sB[2][2];
#pragma unroll
  for (int h=0;h<2;h++){
#pragma unroll
    for (int i=0;i<2;i++){
      int idx = i*512 + tid;
      int r = idx >> 3, seg = idx & 7;
      int sc = (seg ^ (r & 7))*8;
      int br = ((r>>6)<<7) | (h<<6) | (r & 63);   // interleaved A halves (bit6)
      int rr = row0 + br; rr = rr < n_e ? rr : (n_e - 1);
      int tokr = entries[ebase + rr] >> 1;
      sA[h][i] = xb + (size_t)tokr*H_DIM + sc;
      const unsigned short* w = h ? w3b : w1b;    // B part2=w1(gate), part3=w3(up)
      sB[h][i] = w + ((size_t)e*F_DIM + nt*128 + r)*H_DIM + sc;
    }
  }
  int dstb0 = wid*512;
  int dstb1 = 4096 + wid*512;

  int aoff[4][2], boff[2][2];
#pragma unroll
  for (int m=0;m<4;m++){
    int ia = wm*64 + m*16 + (lane & 15);
#pragma unroll
    for (int ks=0;ks<2;ks++)
      aoff[m][ks] = ia*128 + ((ks*64 + (lane>>4)*16) ^ ((ia & 7) << 4));
  }
#pragma unroll
  for (int n=0;n<2;n++){
    int ib = wn*32 + n*16 + (lane & 15);
#pragma unroll
    for (int ks=0;ks<2;ks++)
      boff[n][ks] = ib*128 + ((ks*64 + (lane>>4)*16) ^ ((ib & 7) << 4));
  }

  f32x4 acc[2][2][4][2];
#pragma unroll
  for (int qr=0;qr<2;qr++)
#pragma unroll
  for (int qc=0;qc<2;qc++)
#pragma unroll
  for (int m=0;m<4;m++)
#pragma unroll
  for (int n=0;n<2;n++) acc[qr][qc][m][n] = {0.f,0.f,0.f,0.f};

  bf16x8 a[4][2], bA[2][2], bB[2][2];

  KLOOP16F();

  // SiLU epilogue: gate=acc[qr][0], up=acc[qr][1]
  int r16 = ((lane >> 4) & 3)*4;
#pragma unroll
  for (int qr=0;qr<2;qr++){
#pragma unroll
    for (int m=0;m<4;m++){
#pragma unroll
      for (int j=0;j<4;j++){
        int br = wm*128 + qr*64 + m*16 + r16 + j;
        if (row0 + br < n_e){
          size_t rowbase = (size_t)(ebase + row0 + br)*F_DIM + nt*128 + wn*32;
#pragma unroll
          for (int n=0;n<2;n++){
            float g = acc[qr][0][m][n][j];
            float u = acc[qr][1][m][n][j];
            float h = (g / (1.f + __expf(-g))) * u;
            hidden[rowbase + n*16 + (lane & 15)] = f2bf(h);
          }
        }
      }
    }
  }
}

// ---------------- phase 2: 256x256 grouped GEMM + combine, full K -----------
// A = 256 hidden rows (contiguous, bit6-interleaved halves), B0/B1 = w2 rows
// nt*256..+256 (K-stride F_DIM), full K = 32 K-tiles. Grid 156 = 39 x 4 nt
// -> ONE round on 256 CUs. Bijective XCD chunking (q=19, r=4). Partials
// merged by fp32 atomicAdd (2 adds/elem: one per selected expert).
__global__ __launch_bounds__(512) void k_ffn2(const unsigned short* __restrict__ hidden,
                                              const unsigned short* __restrict__ w2b,
                                              const int* __restrict__ counts,
                                              const int* __restrict__ entries,
                                              const float* __restrict__ topv,
                                              float* __restrict__ out){
  extern __shared__ unsigned short lds[];
  int orig = blockIdx.x;                    // 156 blocks
  int xcd = orig & 7, idx = orig >> 3;
  int base = xcd < 4 ? xcd*20 : 80 + (xcd-4)*19;   // q=19, r=4 bijective
  int nw = base + idx;
  int nt   = nw / MAXT256;                  // 256-col group of H
  int tile = nw % MAXT256;
  int e, ts_e, n_e, btot;
  EXPERT_PREFIX(tile, counts, e, ts_e, n_e, btot);
  if (tile >= btot) return;
  int row0 = (tile - ts_e)*256;
  int ebase = ts_e*256;

  int tid = threadIdx.x, lane = tid & 63, wid = tid >> 6;
  int wm = wid >> 2, wn = wid & 3;          // 2 x 4 wave grid

  const unsigned short* sA[2][2];
  const unsigned short* sB[2][2];
#pragma unroll
  for (int h=0;h<2;h++){
#pragma unroll
    for (int i=0;i<2;i++){
      int idx2 = i*512 + tid;
      int r = idx2 >> 3, seg = idx2 & 7;
      int sc = (seg ^ (r & 7))*8;
      int br = ((r>>6)<<7) | (h<<6) | (r & 63);   // interleaved A halves (bit6)
      sA[h][i] = hidden + (size_t)(ebase + row0 + br)*F_DIM + sc;  // padded rows: stale data, discarded
      sB[h][i] = w2b + ((size_t)e*H_DIM + nt*256 + h*128 + r)*F_DIM + sc;
    }
  }
  int dstb0 = wid*512;
  int dstb1 = 4096 + wid*512;

  int aoff[4][2], boff[2][2];
#pragma unroll
  for (int m=0;m<4;m++){
    int ia = wm*64 + m*16 + (lane & 15);
#pragma unroll
    for (int ks=0;ks<2;ks++)
      aoff[m][ks] = ia*128 + ((ks*64 + (lane>>4)*16) ^ ((ia & 7) << 4));
  }
#pragma unroll
  for (int n=0;n<2;n++){
    int ib = wn*32 + n*16 + (lane & 15);
#pragma unroll
    for (int ks=0;ks<2;ks++)
      boff[n][ks] = ib*128 + ((ks*64 + (lane>>4)*16) ^ ((ib & 7) << 4));
  }

  f32x4 acc[2][2][4][2];
#pragma unroll
  for (int qr=0;qr<2;qr++)
#pragma unroll
  for (int qc=0;qc<2;qc++)
#pragma unroll
  for (int m=0;m<4;m++)
#pragma unroll
  for (int n=0;n<2;n++) acc[qr][qc][m][n] = {0.f,0.f,0.f,0.f};

  bf16x8 a[4][2], bA[2][2], bB[2][2];

  KLOOP32F();

  // weighted combine: acc[qr][qc] -> out cols nt*256 + qc*128 + wn*32 + ...
  int r16 = ((lane >> 4) & 3)*4;
#pragma unroll
  for (int qr=0;qr<2;qr++){
#pragma unroll
    for (int m=0;m<4;m++){
#pragma unroll
      for (int j=0;j<4;j++){
        int gr = row0 + wm*128 + qr*64 + m*16 + r16 + j;
        if (gr < n_e){
          int packed = entries[ebase + gr];
          int t = packed >> 1;
          float w = topv[packed];
#pragma unroll
          for (int qc=0;qc<2;qc++){
#pragma unroll
            for (int n=0;n<2;n++){
              int col = nt*256 + qc*128 + wn*32 + n*16 + (lane & 15);
              atomicAdd(&out[(size_t)t*H_DIM + col], w * acc[qr][qc][m][n][j]);
            }
          }
        }
      }
    }
  }
}

// ---------------------------------------------------------------------------
extern "C" void kernel_launch(void* const* d_in, const int* in_sizes, int n_in,
                              void* d_out, int out_size, void* d_ws, size_t ws_size,
                              hipStream_t stream){
  const float* x  = (const float*)d_in[0];
  const float* rw = (const float*)d_in[1];
  const float* w1 = (const float*)d_in[2];
  const float* w2 = (const float*)d_in[3];
  const float* w3 = (const float*)d_in[4];
  float* out = (float*)d_out;

  char* ws = (char*)d_ws;
  size_t off = 0;
  unsigned short* xb  = (unsigned short*)(ws + off); off += (size_t)T_TOK*H_DIM*2;
  unsigned short* w1b = (unsigned short*)(ws + off); off += (size_t)E_NUM*F_DIM*H_DIM*2;
  unsigned short* w3b = (unsigned short*)(ws + off); off += (size_t)E_NUM*F_DIM*H_DIM*2;
  unsigned short* w2b = (unsigned short*)(ws + off); off += (size_t)E_NUM*H_DIM*F_DIM*2;
  unsigned short* hidden = (unsigned short*)(ws + off); off += (size_t)MAXROWS*F_DIM*2;
  int*   counts  = (int*)(ws + off); off += 64;   // [16] ints
  int*   cursors = (int*)(ws + off); off += 64;   // [16] ints (counts+cursors = zbase[32])
  int*   topi    = (int*)(ws + off); off += (size_t)T_TOK*2*4;
  float* topv    = (float*)(ws + off); off += (size_t)T_TOK*2*4;
  int*   entries = (int*)(ws + off); off += (size_t)MAXROWS*4;

  hipFuncSetAttribute((const void*)k_ffn1,
                      hipFuncAttributeMaxDynamicSharedMemorySize, 131072);
  hipFuncSetAttribute((const void*)k_ffn2,
                      hipFuncAttributeMaxDynamicSharedMemorySize, 131072);

  k_wcvt<<<3*2048, 256, 0, stream>>>(w1, w3, w2, w1b, w3b, w2b, out, counts);
  k_router<<<T_TOK/32, 256, 0, stream>>>(x, rw, counts, topi, topv, xb);
  k_fill<<<T_TOK/256, 256, 0, stream>>>(topi, counts, cursors, entries);
  k_ffn1<<<MAXT256*16, 512, 131072, stream>>>(xb, w1b, w3b, counts, entries, hidden);
  k_ffn2<<<MAXT256*4, 512, 131072, stream>>>(hidden, w2b, counts, entries, topv, out);
}

// Round 10
// 284.578 us; speedup vs baseline: 1.1706x; 1.0567x over previous
//
#include <hip/hip_runtime.h>
#include <hip/hip_bf16.h>
#include <cstdint>

#define T_TOK 4096
#define H_DIM 1024
#define F_DIM 2048
#define E_NUM 8
#define MAXT256 39
#define MAXROWS (MAXT256*256)   // 9984 padded entry rows

typedef __attribute__((ext_vector_type(8))) short bf16x8;
typedef __attribute__((ext_vector_type(4))) float f32x4;

__device__ __forceinline__ unsigned short f2bf(float f){
  union { float f; uint32_t u; } c; c.f = f;
  uint32_t u = c.u;
  uint32_t r = (u + 0x7fffu + ((u >> 16) & 1u)) >> 16;
  return (unsigned short)r;
}

// expert lookup from counts via unrolled prefix
#define EXPERT_PREFIX(tile, counts, e, ts_e, n_e, btot) do{ \
  btot = 0; e = 0; ts_e = 0; n_e = 0; \
  _Pragma("unroll") for (int i_=0;i_<E_NUM;i_++){ \
    int cnt_ = (counts)[i_]; \
    if ((tile) >= btot){ e = i_; ts_e = btot; n_e = cnt_; } \
    btot += (cnt_ + 255) >> 8; } }while(0)

// ---- weights fp32 -> bf16 (3 segments) + zero counts/cursors + zero out ----
__global__ __launch_bounds__(256) void k_wcvt(const float* __restrict__ w1,
                                              const float* __restrict__ w3,
                                              const float* __restrict__ w2,
                                              unsigned short* __restrict__ w1b,
                                              unsigned short* __restrict__ w3b,
                                              unsigned short* __restrict__ w2b,
                                              float* __restrict__ out,
                                              int* __restrict__ zbase){
  int tid = threadIdx.x;
  if (blockIdx.x == 0 && tid < 32) zbase[tid] = 0;   // counts[16] + cursors[16]
  float4 z4 = {0.f,0.f,0.f,0.f};
  for (int i = blockIdx.x*256 + tid; i < T_TOK*H_DIM/4; i += 6144*256)
    reinterpret_cast<float4*>(out)[i] = z4;
  int seg = blockIdx.x >> 11;
  int b   = blockIdx.x & 2047;
  const float* s = seg==0 ? w1 : (seg==1 ? w3 : w2);
  unsigned short* d = seg==0 ? w1b : (seg==1 ? w3b : w2b);
  const int n4 = E_NUM*F_DIM*H_DIM/4;
  for (int i = b*256 + tid; i < n4; i += 2048*256){
    float4 v = reinterpret_cast<const float4*>(s)[i];
    ushort4 o;
    o.x = f2bf(v.x); o.y = f2bf(v.y); o.z = f2bf(v.z); o.w = f2bf(v.w);
    reinterpret_cast<ushort4*>(d)[i] = o;
  }
}

// ------- router: 32 tokens/block, 8 lanes/token, rw staged in LDS -----------
__global__ __launch_bounds__(256) void k_router(const float* __restrict__ x,
                                               const float* __restrict__ rw,
                                               int* __restrict__ counts,
                                               int* __restrict__ topi,
                                               float* __restrict__ topv,
                                               unsigned short* __restrict__ xb){
  __shared__ float lrw[E_NUM][8][132];
  __shared__ int hist[E_NUM];
  int tid = threadIdx.x;
  if (tid < E_NUM) hist[tid] = 0;
  for (int i = tid; i < E_NUM*H_DIM/4; i += 256){
    int idx = i*4;
    int e = idx >> 10, rem = idx & 1023, c = rem >> 7, j = rem & 127;
    float4 v = reinterpret_cast<const float4*>(rw)[i];
    *reinterpret_cast<float4*>(&lrw[e][c][j]) = v;
  }
  __syncthreads();

  int t = blockIdx.x*32 + (tid >> 3);
  int c = tid & 7;
  const float4* xr = reinterpret_cast<const float4*>(x + (size_t)t*H_DIM + c*128);
  ushort4* xw = reinterpret_cast<ushort4*>(xb + (size_t)t*H_DIM + c*128);
  double acc[E_NUM];
#pragma unroll
  for (int e=0;e<E_NUM;e++) acc[e] = 0.0;
  for (int j4=0; j4<32; ++j4){
    float4 v = xr[j4];
    ushort4 o;
    o.x = f2bf(v.x); o.y = f2bf(v.y); o.z = f2bf(v.z); o.w = f2bf(v.w);
    xw[j4] = o;
#pragma unroll
    for (int e=0;e<E_NUM;e++){
      float4 r = *reinterpret_cast<const float4*>(&lrw[e][c][j4*4]);
      acc[e] += (double)v.x*(double)r.x + (double)v.y*(double)r.y
              + (double)v.z*(double)r.z + (double)v.w*(double)r.w;
    }
  }
#pragma unroll
  for (int e=0;e<E_NUM;e++){
    double s = acc[e];
    s += __shfl_xor(s, 1, 64);
    s += __shfl_xor(s, 2, 64);
    s += __shfl_xor(s, 4, 64);
    acc[e] = s;
  }
  if (c == 0){
    int i0 = 0; double v0 = acc[0];
    for (int e=1;e<E_NUM;e++) if (acc[e] > v0){ v0 = acc[e]; i0 = e; }
    int i1 = -1; double v1 = -1e300;
    for (int e=0;e<E_NUM;e++) if (e != i0 && acc[e] > v1){ v1 = acc[e]; i1 = e; }
    float w0 = 1.0f/(1.0f + expf((float)(v1 - v0)));
    topi[2*t] = i0; topi[2*t+1] = i1;
    topv[2*t] = w0; topv[2*t+1] = 1.0f - w0;
    atomicAdd(&hist[i0], 1); atomicAdd(&hist[i1], 1);
  }
  __syncthreads();
  if (tid < E_NUM && hist[tid]) atomicAdd(&counts[tid], hist[tid]);
}

// ---------------- fill grouped entry lists (prefix computed locally) --------
__global__ __launch_bounds__(256) void k_fill(const int* __restrict__ topi,
                                              const int* __restrict__ counts,
                                              int* __restrict__ cursors,
                                              int* __restrict__ entries){
  __shared__ int ts[E_NUM];
  if (threadIdx.x == 0){
    int b = 0;
    for (int e=0;e<E_NUM;e++){ ts[e] = b; b += (counts[e] + 255) >> 8; }
  }
  __syncthreads();
  int t = blockIdx.x*256 + threadIdx.x;
  if (t >= T_TOK) return;
#pragma unroll
  for (int k=0;k<2;k++){
    int e = topi[2*t+k];
    int pos = atomicAdd(&cursors[e], 1);
    entries[ts[e]*256 + pos] = 2*t + k;
  }
}

// ---------------- shared sync / staging macros ------------------------------
#define GLD(src, dst_us) __builtin_amdgcn_global_load_lds( \
  (const __attribute__((address_space(1))) unsigned int*)(src), \
  (__attribute__((address_space(3))) unsigned int*)(lds + (dst_us)), 16, 0, 0)

#define VMW(N) asm volatile("s_waitcnt vmcnt(" #N ")" ::: "memory")
#define BARS do{ __builtin_amdgcn_s_barrier(); __builtin_amdgcn_sched_barrier(0); }while(0)
#define MMGO do{ asm volatile("s_waitcnt lgkmcnt(0)" ::: "memory"); \
  __builtin_amdgcn_sched_barrier(0); __builtin_amdgcn_s_setprio(1); }while(0)
#define MMEND __builtin_amdgcn_s_setprio(0)

// ---------------- 256x256 3-phase K-loop (measured-best cadence) ------------
// Parts per 64KiB buffer: 0=A0, 1=A1, 2=B0, 3=B1. 3 phases/K-tile,
// VMW(4)/VMW(6)/VMW(8), one barrier per phase, stage into the other dbuf.

#define STG(X, s0, s1, dbS, kS) do{ \
  GLD((s0) + (kS)*64, (dbS)*32768 + (X)*8192 + dstb0); \
  GLD((s1) + (kS)*64, (dbS)*32768 + (X)*8192 + dstb1); }while(0)

#define LDA(db, QR) do{ const char* p_ = (const char*)lds + ((db)*4 + (QR))*16384; \
  _Pragma("unroll") for (int m_=0;m_<4;m_++) \
  _Pragma("unroll") for (int ks_=0;ks_<2;ks_++) \
    a[m_][ks_] = *(const bf16x8*)(p_ + aoff[m_][ks_]); }while(0)

#define LDB(db, QC, breg) do{ const char* p_ = (const char*)lds + ((db)*4 + 2 + (QC))*16384; \
  _Pragma("unroll") for (int n_=0;n_<2;n_++) \
  _Pragma("unroll") for (int ks_=0;ks_<2;ks_++) \
    breg[n_][ks_] = *(const bf16x8*)(p_ + boff[n_][ks_]); }while(0)

#define MM(QR, QC, breg) do{ \
  _Pragma("unroll") for (int m_=0;m_<4;m_++) \
  _Pragma("unroll") for (int n_=0;n_<2;n_++) \
  _Pragma("unroll") for (int ks_=0;ks_<2;ks_++) \
    acc[QR][QC][m_][n_] = __builtin_amdgcn_mfma_f32_16x16x32_bf16(a[m_][ks_], breg[n_][ks_], acc[QR][QC][m_][n_], 0,0,0); }while(0)

// NTILES-K-tile double-buffered main loop + drain epilogue (NTILES even)
#define KLOOP(NTILES) do{ \
  STG(0, sA[0][0], sA[0][1], 0, 0); \
  STG(2, sB[0][0], sB[0][1], 0, 0); \
  STG(3, sB[1][0], sB[1][1], 0, 0); \
  STG(1, sA[1][0], sA[1][1], 0, 0); \
  for (int T=0; T<(NTILES)-1; ++T){ \
    int db = T & 1, dbS = db ^ 1, kS = T + 1; \
    VMW(4); BARS; \
    if (db == 0){ LDA(0,0); LDB(0,0,bA); } else { LDA(1,0); LDB(1,0,bA); } \
    STG(0, sA[0][0], sA[0][1], dbS, kS); \
    STG(2, sB[0][0], sB[0][1], dbS, kS); \
    MMGO; MM(0,0,bA); MMEND; \
    VMW(6); BARS; \
    if (db == 0){ LDB(0,1,bB); } else { LDB(1,1,bB); } \
    STG(3, sB[1][0], sB[1][1], dbS, kS); \
    STG(1, sA[1][0], sA[1][1], dbS, kS); \
    MMGO; MM(0,1,bB); MMEND; \
    VMW(8); BARS; \
    if (db == 0){ LDA(0,1); } else { LDA(1,1); } \
    MMGO; MM(1,0,bA); MM(1,1,bB); MMEND; \
  } \
  VMW(4); BARS; LDA(1,0); LDB(1,0,bA); MMGO; MM(0,0,bA); MMEND; \
  VMW(2); BARS; LDB(1,1,bB);           MMGO; MM(0,1,bB); MMEND; \
  VMW(0); BARS; LDA(1,1);              MMGO; MM(1,0,bA); MM(1,1,bB); MMEND; }while(0)

// ---------------- phase 1: 256x256 grouped GEMM + SiLU ----------------------
__global__ __launch_bounds__(512) void k_ffn1(const unsigned short* __restrict__ xb,
                                              const unsigned short* __restrict__ w1b,
                                              const unsigned short* __restrict__ w3b,
                                              const int* __restrict__ counts,
                                              const int* __restrict__ entries,
                                              unsigned short* __restrict__ hidden){
  extern __shared__ unsigned short lds[];
  int flat = blockIdx.x;
  int nw = (flat & 7)*78 + (flat >> 3);     // 624 = 8*78 bijective XCD chunking
  int tile = nw % MAXT256;
  int nt   = nw / MAXT256;
  int e, ts_e, n_e, btot;
  EXPERT_PREFIX(tile, counts, e, ts_e, n_e, btot);
  if (tile >= btot) return;
  int row0 = (tile - ts_e)*256;
  int ebase = ts_e*256;

  int tid = threadIdx.x, lane = tid & 63, wid = tid >> 6;
  int wm = wid >> 2, wn = wid & 3;          // 2 x 4 wave grid

  const unsigned short* sA[2][2];
  const unsigned short* sB[2][2];
#pragma unroll
  for (int h=0;h<2;h++){
#pragma unroll
    for (int i=0;i<2;i++){
      int idx = i*512 + tid;
      int r = idx >> 3, seg = idx & 7;
      int sc = (seg ^ (r & 7))*8;
      int br = ((r>>6)<<7) | (h<<6) | (r & 63);   // interleaved A halves (bit6)
      int rr = row0 + br; rr = rr < n_e ? rr : (n_e - 1);
      int tokr = entries[ebase + rr] >> 1;
      sA[h][i] = xb + (size_t)tokr*H_DIM + sc;
      const unsigned short* w = h ? w3b : w1b;    // B part2=w1(gate), part3=w3(up)
      sB[h][i] = w + ((size_t)e*F_DIM + nt*128 + r)*H_DIM + sc;
    }
  }
  int dstb0 = wid*512;
  int dstb1 = 4096 + wid*512;

  int aoff[4][2], boff[2][2];
#pragma unroll
  for (int m=0;m<4;m++){
    int ia = wm*64 + m*16 + (lane & 15);
#pragma unroll
    for (int ks=0;ks<2;ks++)
      aoff[m][ks] = ia*128 + ((ks*64 + (lane>>4)*16) ^ ((ia & 7) << 4));
  }
#pragma unroll
  for (int n=0;n<2;n++){
    int ib = wn*32 + n*16 + (lane & 15);
#pragma unroll
    for (int ks=0;ks<2;ks++)
      boff[n][ks] = ib*128 + ((ks*64 + (lane>>4)*16) ^ ((ib & 7) << 4));
  }

  f32x4 acc[2][2][4][2];
#pragma unroll
  for (int qr=0;qr<2;qr++)
#pragma unroll
  for (int qc=0;qc<2;qc++)
#pragma unroll
  for (int m=0;m<4;m++)
#pragma unroll
  for (int n=0;n<2;n++) acc[qr][qc][m][n] = {0.f,0.f,0.f,0.f};

  bf16x8 a[4][2], bA[2][2], bB[2][2];

  KLOOP(16);

  // SiLU epilogue: gate=acc[qr][0], up=acc[qr][1]
  int r16 = ((lane >> 4) & 3)*4;
#pragma unroll
  for (int qr=0;qr<2;qr++){
#pragma unroll
    for (int m=0;m<4;m++){
#pragma unroll
      for (int j=0;j<4;j++){
        int br = wm*128 + qr*64 + m*16 + r16 + j;
        if (row0 + br < n_e){
          size_t rowbase = (size_t)(ebase + row0 + br)*F_DIM + nt*128 + wn*32;
#pragma unroll
          for (int n=0;n<2;n++){
            float g = acc[qr][0][m][n][j];
            float u = acc[qr][1][m][n][j];
            float h = (g / (1.f + __expf(-g))) * u;
            hidden[rowbase + n*16 + (lane & 15)] = f2bf(h);
          }
        }
      }
    }
  }
}

// ---------------- phase 2: 256x256 grouped GEMM + combine, full K -----------
// A = 256 hidden rows (contiguous, bit6-interleaved halves), B0/B1 = w2 rows
// nt*256..+256 (K-stride F_DIM), full K = 32 K-tiles via the same 3-phase
// ledger. Grid 156 = 39 x 4 nt -> ONE round on 256 CUs, bijective XCD
// chunking (q=19, r=4). Partials merged by fp32 atomicAdd (2 adds/elem).
__global__ __launch_bounds__(512) void k_ffn2(const unsigned short* __restrict__ hidden,
                                              const unsigned short* __restrict__ w2b,
                                              const int* __restrict__ counts,
                                              const int* __restrict__ entries,
                                              const float* __restrict__ topv,
                                              float* __restrict__ out){
  extern __shared__ unsigned short lds[];
  int orig = blockIdx.x;                    // 156 blocks
  int xcd = orig & 7, idx = orig >> 3;
  int base = xcd < 4 ? xcd*20 : 80 + (xcd-4)*19;   // q=19, r=4 bijective
  int nw = base + idx;
  int nt   = nw / MAXT256;                  // 256-col group of H
  int tile = nw % MAXT256;
  int e, ts_e, n_e, btot;
  EXPERT_PREFIX(tile, counts, e, ts_e, n_e, btot);
  if (tile >= btot) return;
  int row0 = (tile - ts_e)*256;
  int ebase = ts_e*256;

  int tid = threadIdx.x, lane = tid & 63, wid = tid >> 6;
  int wm = wid >> 2, wn = wid & 3;          // 2 x 4 wave grid

  const unsigned short* sA[2][2];
  const unsigned short* sB[2][2];
#pragma unroll
  for (int h=0;h<2;h++){
#pragma unroll
    for (int i=0;i<2;i++){
      int idx2 = i*512 + tid;
      int r = idx2 >> 3, seg = idx2 & 7;
      int sc = (seg ^ (r & 7))*8;
      int br = ((r>>6)<<7) | (h<<6) | (r & 63);   // interleaved A halves (bit6)
      sA[h][i] = hidden + (size_t)(ebase + row0 + br)*F_DIM + sc;  // padded rows: stale data, discarded
      sB[h][i] = w2b + ((size_t)e*H_DIM + nt*256 + h*128 + r)*F_DIM + sc;
    }
  }
  int dstb0 = wid*512;
  int dstb1 = 4096 + wid*512;

  int aoff[4][2], boff[2][2];
#pragma unroll
  for (int m=0;m<4;m++){
    int ia = wm*64 + m*16 + (lane & 15);
#pragma unroll
    for (int ks=0;ks<2;ks++)
      aoff[m][ks] = ia*128 + ((ks*64 + (lane>>4)*16) ^ ((ia & 7) << 4));
  }
#pragma unroll
  for (int n=0;n<2;n++){
    int ib = wn*32 + n*16 + (lane & 15);
#pragma unroll
    for (int ks=0;ks<2;ks++)
      boff[n][ks] = ib*128 + ((ks*64 + (lane>>4)*16) ^ ((ib & 7) << 4));
  }

  f32x4 acc[2][2][4][2];
#pragma unroll
  for (int qr=0;qr<2;qr++)
#pragma unroll
  for (int qc=0;qc<2;qc++)
#pragma unroll
  for (int m=0;m<4;m++)
#pragma unroll
  for (int n=0;n<2;n++) acc[qr][qc][m][n] = {0.f,0.f,0.f,0.f};

  bf16x8 a[4][2], bA[2][2], bB[2][2];

  KLOOP(32);

  // weighted combine: acc[qr][qc] -> out cols nt*256 + qc*128 + wn*32 + ...
  int r16 = ((lane >> 4) & 3)*4;
#pragma unroll
  for (int qr=0;qr<2;qr++){
#pragma unroll
    for (int m=0;m<4;m++){
#pragma unroll
      for (int j=0;j<4;j++){
        int gr = row0 + wm*128 + qr*64 + m*16 + r16 + j;
        if (gr < n_e){
          int packed = entries[ebase + gr];
          int t = packed >> 1;
          float w = topv[packed];
#pragma unroll
          for (int qc=0;qc<2;qc++){
#pragma unroll
            for (int n=0;n<2;n++){
              int col = nt*256 + qc*128 + wn*32 + n*16 + (lane & 15);
              atomicAdd(&out[(size_t)t*H_DIM + col], w * acc[qr][qc][m][n][j]);
            }
          }
        }
      }
    }
  }
}

// ---------------------------------------------------------------------------
extern "C" void kernel_launch(void* const* d_in, const int* in_sizes, int n_in,
                              void* d_out, int out_size, void* d_ws, size_t ws_size,
                              hipStream_t stream){
  const float* x  = (const float*)d_in[0];
  const float* rw = (const float*)d_in[1];
  const float* w1 = (const float*)d_in[2];
  const float* w2 = (const float*)d_in[3];
  const float* w3 = (const float*)d_in[4];
  float* out = (float*)d_out;

  char* ws = (char*)d_ws;
  size_t off = 0;
  unsigned short* xb  = (unsigned short*)(ws + off); off += (size_t)T_TOK*H_DIM*2;
  unsigned short* w1b = (unsigned short*)(ws + off); off += (size_t)E_NUM*F_DIM*H_DIM*2;
  unsigned short* w3b = (unsigned short*)(ws + off); off += (size_t)E_NUM*F_DIM*H_DIM*2;
  unsigned short* w2b = (unsigned short*)(ws + off); off += (size_t)E_NUM*H_DIM*F_DIM*2;
  unsigned short* hidden = (unsigned short*)(ws + off); off += (size_t)MAXROWS*F_DIM*2;
  int*   counts  = (int*)(ws + off); off += 64;   // [16] ints
  int*   cursors = (int*)(ws + off); off += 64;   // [16] ints (counts+cursors = zbase[32])
  int*   topi    = (int*)(ws + off); off += (size_t)T_TOK*2*4;
  float* topv    = (float*)(ws + off); off += (size_t)T_TOK*2*4;
  int*   entries = (int*)(ws + off); off += (size_t)MAXROWS*4;

  hipFuncSetAttribute((const void*)k_ffn1,
                      hipFuncAttributeMaxDynamicSharedMemorySize, 131072);
  hipFuncSetAttribute((const void*)k_ffn2,
                      hipFuncAttributeMaxDynamicSharedMemorySize, 131072);

  k_wcvt<<<3*2048, 256, 0, stream>>>(w1, w3, w2, w1b, w3b, w2b, out, counts);
  k_router<<<T_TOK/32, 256, 0, stream>>>(x, rw, counts, topi, topv, xb);
  k_fill<<<T_TOK/256, 256, 0, stream>>>(topi, counts, cursors, entries);
  k_ffn1<<<MAXT256*16, 512, 131072, stream>>>(xb, w1b, w3b, counts, entries, hidden);
  k_ffn2<<<MAXT256*4, 512, 131072, stream>>>(hidden, w2b, counts, entries, topv, out);
}